// Round 14
// baseline (434.409 us; speedup 1.0000x reference)
//
#include <hip/hip_runtime.h>
#include <hip/hip_bf16.h>
#include <math.h>
#include <stdint.h>

typedef __bf16 bf16;
typedef __bf16 bf16x8 __attribute__((ext_vector_type(8)));
typedef __bf16 bf16x4 __attribute__((ext_vector_type(4)));
typedef float f32x4 __attribute__((ext_vector_type(4)));

#define AS1 __attribute__((address_space(1)))
#define AS3 __attribute__((address_space(3)))

#define NPIX (16*56*56)          // 50176 pixels
#define CH 256
#define SCALE_K 0.17677669529663687f   // 32^-0.5

// gelu(tanh form) == vv * sigmoid(2u); exp2/rcp raw instructions.
__device__ __forceinline__ float gelu_fast(float vv) {
    float t = vv * (-2.30220781f + -0.10294330f * vv * vv);
    float e = __builtin_amdgcn_exp2f(t);
    return vv * __builtin_amdgcn_rcpf(1.0f + e);
}

// ------- fused: [0,12544) posconv+LN1 blocks; [12544,15619) weight prep --
// x1 stored bf16 (residual only; LN1 computed from fp32 regs).
__global__ __launch_bounds__(256) void pre_kernel(
    const float* __restrict__ x, const float* __restrict__ pos_w,
    const float* __restrict__ pos_b, const float* __restrict__ ln1_g,
    const float* __restrict__ ln1_b, bf16* __restrict__ x1,
    bf16* __restrict__ tln,
    const float* __restrict__ q_w, const float* __restrict__ k_w,
    const float* __restrict__ v_w, const float* __restrict__ out_w,
    const float* __restrict__ fc1_w, const float* __restrict__ fc2_w,
    const float* __restrict__ qb, const float* __restrict__ kb,
    const float* __restrict__ vb,
    bf16* __restrict__ wt_qkv, bf16* __restrict__ wt_out,
    bf16* __restrict__ wt_fc1, bf16* __restrict__ wt_fc2,
    float* __restrict__ qkvb)
{
    if (blockIdx.x >= 12544) {
        int idx = (blockIdx.x - 12544) * 256 + threadIdx.x;
        if (idx < 262144) {
            int w = idx >> 16;                 // 0=q 1=k 2=v 3=out
            int j = idx & 65535;
            int n = j >> 8, k = j & 255;
            const float* src = (w == 0) ? q_w : (w == 1) ? k_w : (w == 2) ? v_w : out_w;
            float scale = (w == 1) ? SCALE_K : 1.0f;
            bf16* dst = (w < 3) ? (wt_qkv + w * 65536) : wt_out;
            dst[j] = (bf16)(src[k * 256 + n] * scale);
        } else if (idx < 524288) {
            int j = idx - 262144;
            int n = j >> 8, k = j & 255;
            wt_fc1[j] = (bf16)(fc1_w[k * 1024 + n]);
        } else if (idx < 786432) {
            int j = idx - 524288;
            int n = j >> 10, k = j & 1023;
            wt_fc2[j] = (bf16)(fc2_w[k * 256 + n]);
        } else if (idx < 787200) {
            int i = idx - 786432;
            qkvb[i] = (i < 256) ? qb[i] : (i < 512) ? kb[i - 256] * SCALE_K : vb[i - 512];
        }
        return;
    }
    const int wave = threadIdx.x >> 6, lane = threadIdx.x & 63;
    const long pix = (long)blockIdx.x * 4 + wave;
    const int ww = (int)(pix % 56);
    const int hh = (int)((pix / 56) % 56);
    const int b  = (int)(pix / 3136);
    const int c  = lane * 4;
    float4 acc = ((const float4*)(pos_b + c))[0];
    float4 xin = ((const float4*)(x + pix * 256 + c))[0];
    acc.x += xin.x; acc.y += xin.y; acc.z += xin.z; acc.w += xin.w;
    #pragma unroll
    for (int dh = 0; dh < 3; ++dh) {
        int h2 = hh + dh - 1;
        if (h2 < 0 || h2 >= 56) continue;
        #pragma unroll
        for (int dw = 0; dw < 3; ++dw) {
            int w2 = ww + dw - 1;
            if (w2 < 0 || w2 >= 56) continue;
            float4 xv = ((const float4*)(x + (((long)(b * 56 + h2)) * 56 + w2) * 256 + c))[0];
            float4 wv = ((const float4*)(pos_w + (dh * 3 + dw) * 256 + c))[0];
            acc.x += xv.x * wv.x; acc.y += xv.y * wv.y;
            acc.z += xv.z * wv.z; acc.w += xv.w * wv.w;
        }
    }
    bf16* x1o = x1 + pix * 256 + c;
    x1o[0] = (bf16)acc.x; x1o[1] = (bf16)acc.y;
    x1o[2] = (bf16)acc.z; x1o[3] = (bf16)acc.w;
    float s  = acc.x + acc.y + acc.z + acc.w;
    float q2 = acc.x * acc.x + acc.y * acc.y + acc.z * acc.z + acc.w * acc.w;
    #pragma unroll
    for (int o = 32; o; o >>= 1) {
        s  += __shfl_xor(s,  o, 64);
        q2 += __shfl_xor(q2, o, 64);
    }
    float mean = s * (1.0f / 256.0f);
    float var  = q2 * (1.0f / 256.0f) - mean * mean;
    float rs   = rsqrtf(var + 1e-6f);
    float4 gv = ((const float4*)ln1_g)[lane];
    float4 bv = ((const float4*)ln1_b)[lane];
    bf16* o4 = tln + pix * 256 + c;
    o4[0] = (bf16)((acc.x - mean) * rs * gv.x + bv.x);
    o4[1] = (bf16)((acc.y - mean) * rs * gv.y + bv.y);
    o4[2] = (bf16)((acc.z - mean) * rs * gv.z + bv.z);
    o4[3] = (bf16)((acc.w - mean) * rs * gv.w + bv.w);
}

// ---------------- MFMA attention body: one wave per (b, line, head) ------
template<bool WIDTH>
__device__ __forceinline__ void attn_body(
    int task,
    const bf16* __restrict__ qp, const bf16* __restrict__ kp,
    const bf16* __restrict__ vsrc, const float* __restrict__ mask,
    const bf16* __restrict__ lepe, bf16* __restrict__ outp)
{
    __shared__ bf16 VtAll[4][32][72];   // V^T per wave: rows=d(32), cols=pos(64,swz)
    __shared__ bf16 PlAll[4][16][72];   // P per q-tile: rows=q_local(16), cols=kp(64)
    const int tid = threadIdx.x;
    const int wave = tid >> 6, lane = tid & 63;
    const int g = lane >> 4, ql = lane & 15;
    const int n  = task / 224;                  // head
    const int s  = (task % 224) * 4 + wave;     // slab: b*56 + line
    const int b  = s / 56, rc = s % 56;
    bf16 (*Vt)[72] = VtAll[wave];
    bf16 (*Pl)[72] = PlAll[wave];
    const long basePix = WIDTH ? ((long)(b * 56 + rc)) * 56 : (long)b * 3136 + rc;
    const long pixStride = WIDTH ? 1 : 56;
    const long stride = pixStride * 256;
    const bf16* qb = qp + basePix * 256 + n * 32;
    const bf16* kb = kp + basePix * 256 + n * 32;
    const bf16* vbp = vsrc + basePix * 256 + n * 32;

    #pragma unroll
    for (int it = 0; it < 2; ++it) {
        int idx = it * 64 + lane;
        if (idx < 112) {
            int pp = idx >> 2, chunk = idx & 3;
            int pos0 = pp * 2;
            bf16x8 v0 = *(const bf16x8*)(vbp + (long)pos0 * stride + chunk * 8);
            bf16x8 v1 = *(const bf16x8*)(vbp + (long)(pos0 + 1) * stride + chunk * 8);
            int colb = pos0 ^ (chunk << 3);
            #pragma unroll
            for (int j = 0; j < 8; ++j) {
                union { bf16 h[2]; unsigned int u; } pk;
                pk.h[0] = v0[j]; pk.h[1] = v1[j];
                *(unsigned int*)&Vt[chunk * 8 + j][colb] = pk.u;
            }
        }
    }
    if (lane < 32) {
        int d = lane;
        int colb = 56 ^ ((d >> 3) << 3);
        *(float4*)&Vt[d][colb] = (float4){0.f, 0.f, 0.f, 0.f};
    }

    bf16x8 qf[4], kf[4];
    #pragma unroll
    for (int t4 = 0; t4 < 4; ++t4) {
        int row = ql + 16 * t4; if (row > 55) row = 55;
        qf[t4] = *(const bf16x8*)(qb + (long)row * stride + 8 * g);
        kf[t4] = *(const bf16x8*)(kb + (long)row * stride + 8 * g);
    }

    f32x4 sA[4][4];
    __builtin_amdgcn_s_setprio(1);
    #pragma unroll
    for (int qt = 0; qt < 4; ++qt)
        #pragma unroll
        for (int kt = 0; kt < 4; ++kt)
            sA[qt][kt] = __builtin_amdgcn_mfma_f32_16x16x32_bf16(
                kf[kt], qf[qt], (f32x4){0.f, 0.f, 0.f, 0.f}, 0, 0, 0);
    __builtin_amdgcn_s_setprio(0);

    const float* mrow = mask + n * 3136;
    #pragma unroll
    for (int qt = 0; qt < 4; ++qt) {
        int qm = ql + 16 * qt; if (qm > 55) qm = 55;
        #pragma unroll
        for (int kt = 0; kt < 4; ++kt) {
            if (kt == 3 && g >= 2) {
                sA[qt][3][0] = -3.0e38f; sA[qt][3][1] = -3.0e38f;
                sA[qt][3][2] = -3.0e38f; sA[qt][3][3] = -3.0e38f;
            } else {
                float4 mv = *(const float4*)(mrow + qm * 56 + kt * 16 + 4 * g);
                sA[qt][kt][0] += mv.x; sA[qt][kt][1] += mv.y;
                sA[qt][kt][2] += mv.z; sA[qt][kt][3] += mv.w;
            }
        }
    }

    #pragma unroll
    for (int qt = 0; qt < 4; ++qt) {
        float m = -3.0e38f;
        #pragma unroll
        for (int kt = 0; kt < 4; ++kt)
            #pragma unroll
            for (int r = 0; r < 4; ++r) m = fmaxf(m, sA[qt][kt][r]);
        m = fmaxf(m, __shfl_xor(m, 16, 64));
        m = fmaxf(m, __shfl_xor(m, 32, 64));
        float p[4][4];
        float sum = 0.f;
        #pragma unroll
        for (int kt = 0; kt < 4; ++kt)
            #pragma unroll
            for (int r = 0; r < 4; ++r) {
                float e = exp2f((sA[qt][kt][r] - m) * 1.4426950408889634f);
                p[kt][r] = e; sum += e;
            }
        sum += __shfl_xor(sum, 16, 64);
        sum += __shfl_xor(sum, 32, 64);
        float rinv = 1.0f / sum;
        #pragma unroll
        for (int kt = 0; kt < 4; ++kt) {
            bf16x4 w;
            #pragma unroll
            for (int r = 0; r < 4; ++r) w[r] = (bf16)(p[kt][r] * rinv);
            *(bf16x4*)&Pl[ql][kt * 16 + 4 * g] = w;
        }
        #pragma unroll
        for (int nt = 0; nt < 2; ++nt) {
            f32x4 o = {0.f, 0.f, 0.f, 0.f};
            __builtin_amdgcn_s_setprio(1);
            #pragma unroll
            for (int ks = 0; ks < 2; ++ks) {
                bf16x8 af = *(const bf16x8*)&Pl[ql][ks * 32 + 8 * g];
                int vrow = ql + 16 * nt;
                int vcol = (ks * 32 + 8 * g) ^ ((vrow >> 3) << 3);
                bf16x8 bv = *(const bf16x8*)&Vt[vrow][vcol];
                o = __builtin_amdgcn_mfma_f32_16x16x32_bf16(af, bv, o, 0, 0, 0);
            }
            __builtin_amdgcn_s_setprio(0);
            if (!(qt == 3 && g >= 2)) {
                #pragma unroll
                for (int r = 0; r < 4; ++r) {
                    int q = 16 * qt + 4 * g + r;
                    long addr = (basePix + (long)q * pixStride) * 256 + n * 32 + nt * 16 + ql;
                    float vv = o[r];
                    if (!WIDTH) vv += (float)lepe[addr];
                    outp[addr] = (bf16)vv;
                }
            }
        }
    }
}

// ------- merged: [0,1792) width-attention; [1792,8064) lepe 5x5 dwconv ---
// Independent producers for attn_h; co-residency overlaps lepe's BW-bound
// loop with attn's MFMA/VALU work.
__global__ __launch_bounds__(256) void attnw_lepe_kernel(
    const bf16* __restrict__ qp, const bf16* __restrict__ kp,
    const bf16* __restrict__ vpl, const float* __restrict__ mask_w,
    bf16* __restrict__ vwb,
    const float* __restrict__ lw, const float* __restrict__ lb,
    bf16* __restrict__ lepeb)
{
    if (blockIdx.x < 1792) {
        attn_body<true>(blockIdx.x, qp, kp, vpl, mask_w, nullptr, vwb);
        return;
    }
    long idx = (long)(blockIdx.x - 1792) * 256 + threadIdx.x;   // pix*32 + c8
    int c8 = (int)(idx & 31);
    long pix = idx >> 5;
    int ww = (int)(pix % 56);
    int hh = (int)((pix / 56) % 56);
    int b  = (int)(pix / 3136);
    int c  = c8 * 8;
    float acc[8];
    #pragma unroll
    for (int j = 0; j < 8; ++j) acc[j] = lb[c + j];
    #pragma unroll
    for (int dh = 0; dh < 5; ++dh) {
        int h2 = hh + dh - 2;
        if (h2 < 0 || h2 >= 56) continue;
        #pragma unroll
        for (int dw = 0; dw < 5; ++dw) {
            int w2 = ww + dw - 2;
            if (w2 < 0 || w2 >= 56) continue;
            bf16x8 vv = *(const bf16x8*)(vpl + (((long)(b * 56 + h2)) * 56 + w2) * 256 + c);
            const float4* wp = (const float4*)(lw + (dh * 5 + dw) * 256 + c);
            float4 w0 = wp[0], w1 = wp[1];
            acc[0] += (float)vv[0] * w0.x; acc[1] += (float)vv[1] * w0.y;
            acc[2] += (float)vv[2] * w0.z; acc[3] += (float)vv[3] * w0.w;
            acc[4] += (float)vv[4] * w1.x; acc[5] += (float)vv[5] * w1.y;
            acc[6] += (float)vv[6] * w1.z; acc[7] += (float)vv[7] * w1.w;
        }
    }
    bf16* o = lepeb + pix * 256 + c;
    #pragma unroll
    for (int j = 0; j < 8; ++j) o[j] = (bf16)acc[j];
}

// ---------------- height-axis attention ----------------------------------
__global__ __launch_bounds__(256) void attnh_kernel(
    const bf16* __restrict__ qp, const bf16* __restrict__ kp,
    const bf16* __restrict__ vwb, const float* __restrict__ mask_h,
    const bf16* __restrict__ lepeb, bf16* __restrict__ obuf)
{
    attn_body<false>(blockIdx.x, qp, kp, vwb, mask_h, lepeb, obuf);
}

// ---------------- bf16 MFMA GEMM: 256x128 tile, 8 waves (4M x 2N) --------
template<bool GELU, bool RESID, bool OUT_BF16, bool QKV3>
__global__ __launch_bounds__(512) void gemm_kernel(
    const bf16* __restrict__ A, const bf16* __restrict__ Wt,
    const float* __restrict__ bias, const float* __restrict__ resid,
    void* __restrict__ Cout, int M, int N, int K)
{
    __shared__ bf16 As[256 * 64];
    __shared__ bf16 Bs[128 * 64];
    const int t = threadIdx.x;
    const int wave = t >> 6, lane = t & 63;
    const int nTilesN = N >> 7;
    const int q8 = gridDim.x >> 3;                    // T1 swizzle (grid % 8 == 0)
    const int o = ((int)blockIdx.x & 7) * q8 + ((int)blockIdx.x >> 3);
    const int tm = o / nTilesN, tn = o % nTilesN;
    const long m0 = (long)tm * 256, n0 = (long)tn * 128;
    const int waveM = (wave >> 1) * 64, waveN = (wave & 1) * 64;
    f32x4 acc[4][4] = {};

    for (int k0 = 0; k0 < K; k0 += 64) {
        #pragma unroll
        for (int i = 0; i < 4; ++i) {                 // A: 2048 chunks of 16B
            int c = i * 512 + t;
            int r = c >> 3, cc = (c & 7) * 8;
            const bf16* ga = A + (m0 + r) * (long)K + k0 + cc;
            __builtin_amdgcn_global_load_lds(
                (const AS1 void*)ga, (AS3 void*)(As + c * 8), 16, 0, 0);
        }
        #pragma unroll
        for (int i = 0; i < 2; ++i) {                 // B: 1024 chunks of 16B
            int c = i * 512 + t;
            int r = c >> 3, cc = (c & 7) * 8;
            const bf16* gb = Wt + (n0 + r) * (long)K + k0 + cc;
            __builtin_amdgcn_global_load_lds(
                (const AS1 void*)gb, (AS3 void*)(Bs + c * 8), 16, 0, 0);
        }
        __syncthreads();
        #pragma unroll
        for (int kk = 0; kk < 2; ++kk) {
            bf16x8 af[4], bfr[4];
            const int krow = kk * 32 + (lane >> 4) * 8;
            #pragma unroll
            for (int fm = 0; fm < 4; ++fm)
                af[fm] = *(const bf16x8*)&As[(waveM + fm * 16 + (lane & 15)) * 64 + krow];
            #pragma unroll
            for (int fn = 0; fn < 4; ++fn)
                bfr[fn] = *(const bf16x8*)&Bs[(waveN + fn * 16 + (lane & 15)) * 64 + krow];
            #pragma unroll
            for (int fm = 0; fm < 4; ++fm)
                #pragma unroll
                for (int fn = 0; fn < 4; ++fn)
                    acc[fm][fn] = __builtin_amdgcn_mfma_f32_16x16x32_bf16(
                        af[fm], bfr[fn], acc[fm][fn], 0, 0, 0);
        }
        __syncthreads();
    }

    #pragma unroll
    for (int fm = 0; fm < 4; ++fm) {
        #pragma unroll
        for (int r = 0; r < 4; ++r) {
            const long m = m0 + waveM + fm * 16 + (lane >> 4) * 4 + r;
            #pragma unroll
            for (int fn = 0; fn < 4; ++fn) {
                const long n = n0 + waveN + fn * 16 + (lane & 15);
                float vv = acc[fm][fn][r] + bias[n];
                if (GELU)  vv = gelu_fast(vv);
                if (RESID) vv += resid[m * N + n];
                if (QKV3) {
                    long pl = n >> 8;
                    ((bf16*)Cout)[pl * (long)NPIX * 256 + m * 256 + (n & 255)] = (bf16)vv;
                } else if (OUT_BF16) {
                    ((bf16*)Cout)[m * N + n] = (bf16)vv;
                } else {
                    ((float*)Cout)[m * N + n] = vv;
                }
            }
        }
    }
}

// ------- fused out-proj GEMM + residual(bf16) + LayerNorm2 --------------
__global__ __launch_bounds__(512) void outln_kernel(
    const bf16* __restrict__ A, const bf16* __restrict__ Wt,
    const float* __restrict__ bias, const bf16* __restrict__ resid,
    const float* __restrict__ g2, const float* __restrict__ b2,
    float* __restrict__ x2out, bf16* __restrict__ uout)
{
    __shared__ bf16 As[128 * 64];
    __shared__ bf16 Bs[256 * 64];
    const int t = threadIdx.x;
    const int wave = t >> 6, lane = t & 63;
    const int g = lane >> 4, ql = lane & 15;
    const int q8 = gridDim.x >> 3;
    const int o = ((int)blockIdx.x & 7) * q8 + ((int)blockIdx.x >> 3);
    const long m0 = (long)o * 128;
    const int waveM = wave * 16;
    f32x4 acc[16] = {};

    for (int k0 = 0; k0 < 256; k0 += 64) {
        #pragma unroll
        for (int i = 0; i < 2; ++i) {                 // A: 1024 chunks
            int c = i * 512 + t;
            int r = c >> 3, cc = (c & 7) * 8;
            const bf16* ga = A + (m0 + r) * 256 + k0 + cc;
            __builtin_amdgcn_global_load_lds(
                (const AS1 void*)ga, (AS3 void*)(As + c * 8), 16, 0, 0);
        }
        #pragma unroll
        for (int i = 0; i < 4; ++i) {                 // B: 2048 chunks
            int c = i * 512 + t;
            int r = c >> 3, cc = (c & 7) * 8;
            const bf16* gb = Wt + r * 256 + k0 + cc;
            __builtin_amdgcn_global_load_lds(
                (const AS1 void*)gb, (AS3 void*)(Bs + c * 8), 16, 0, 0);
        }
        __syncthreads();
        #pragma unroll
        for (int kk = 0; kk < 2; ++kk) {
            const int krow = kk * 32 + g * 8;
            bf16x8 af = *(const bf16x8*)&As[(waveM + ql) * 64 + krow];
            #pragma unroll
            for (int fn = 0; fn < 16; ++fn) {
                bf16x8 bv = *(const bf16x8*)&Bs[(fn * 16 + ql) * 64 + krow];
                acc[fn] = __builtin_amdgcn_mfma_f32_16x16x32_bf16(af, bv, acc[fn], 0, 0, 0);
            }
        }
        __syncthreads();
    }

    float rsum[4] = {}, rsq[4] = {};
    #pragma unroll
    for (int fn = 0; fn < 16; ++fn) {
        const int n = fn * 16 + ql;
        const float bn = bias[n];
        #pragma unroll
        for (int r = 0; r < 4; ++r) {
            const long m = m0 + waveM + g * 4 + r;
            float v = acc[fn][r] + bn + (float)resid[m * 256 + n];
            acc[fn][r] = v;
            rsum[r] += v; rsq[r] += v * v;
        }
    }
    #pragma unroll
    for (int r = 0; r < 4; ++r) {
        float s = rsum[r], q = rsq[r];
        #pragma unroll
        for (int off = 8; off; off >>= 1) {
            s += __shfl_xor(s, off, 64);
            q += __shfl_xor(q, off, 64);
        }
        float mean = s * (1.0f / 256.0f);
        float var  = q * (1.0f / 256.0f) - mean * mean;
        rsum[r] = mean;
        rsq[r]  = rsqrtf(var + 1e-6f);
    }
    #pragma unroll
    for (int fn = 0; fn < 16; ++fn) {
        const int n = fn * 16 + ql;
        const float gn = g2[n], bn2 = b2[n];
        #pragma unroll
        for (int r = 0; r < 4; ++r) {
            const long m = m0 + waveM + g * 4 + r;
            float v = acc[fn][r];
            x2out[m * 256 + n] = v;
            uout[m * 256 + n] = (bf16)((v - rsum[r]) * rsq[r] * gn + bn2);
        }
    }
}

// ------------------------------- launch ----------------------------------
extern "C" void kernel_launch(void* const* d_in, const int* in_sizes, int n_in,
                              void* d_out, int out_size, void* d_ws, size_t ws_size,
                              hipStream_t stream)
{
    (void)in_sizes; (void)n_in; (void)out_size; (void)ws_size;
    const float* x      = (const float*)d_in[0];
    const float* mask_h = (const float*)d_in[1];
    const float* mask_w = (const float*)d_in[2];
    const float* pos_w  = (const float*)d_in[3];
    const float* pos_b  = (const float*)d_in[4];
    const float* ln1_g  = (const float*)d_in[5];
    const float* ln1_b  = (const float*)d_in[6];
    const float* q_w    = (const float*)d_in[7];
    const float* q_b    = (const float*)d_in[8];
    const float* k_w    = (const float*)d_in[9];
    const float* k_b    = (const float*)d_in[10];
    const float* v_w    = (const float*)d_in[11];
    const float* v_b    = (const float*)d_in[12];
    const float* lepe_w = (const float*)d_in[13];
    const float* lepe_b = (const float*)d_in[14];
    const float* out_w  = (const float*)d_in[15];
    const float* out_b  = (const float*)d_in[16];
    const float* ln2_g  = (const float*)d_in[17];
    const float* ln2_b  = (const float*)d_in[18];
    const float* fc1_w  = (const float*)d_in[19];
    const float* fc1_b  = (const float*)d_in[20];
    const float* fc2_w  = (const float*)d_in[21];
    const float* fc2_b  = (const float*)d_in[22];

    char* ws = (char*)d_ws;
    size_t off = 0;
    auto alloc = [&](size_t bytes) -> void* {
        void* p = ws + off;
        off += (bytes + 255) & ~(size_t)255;
        return p;
    };
    const int M = NPIX;
    bf16*  x1     = (bf16*) alloc((size_t)M * 256 * 2);       // x + posconv (bf16 residual)
    bf16*  tln    = (bf16*) alloc((size_t)M * 256 * 2);       // LN1 out
    bf16*  qkv3   = (bf16*) alloc((size_t)M * 768 * 2);       // q|k|v PLANAR (3x M*256)
    bf16*  lepeb  = (bf16*) alloc((size_t)M * 256 * 2);       // lepe; later reused as LN2 out
    bf16*  vwb    = (bf16*) alloc((size_t)M * 256 * 2);       // width-attention output
    bf16*  obuf   = (bf16*) alloc((size_t)M * 256 * 2);       // height-attn out + lepe
    bf16*  wt_qkv = (bf16*) alloc((size_t)768 * 256 * 2);
    bf16*  wt_out = (bf16*) alloc((size_t)256 * 256 * 2);
    bf16*  wt_fc1 = (bf16*) alloc((size_t)1024 * 256 * 2);
    bf16*  wt_fc2 = (bf16*) alloc((size_t)256 * 1024 * 2);
    float* qkvb   = (float*)alloc(768 * 4);
    bf16*  qpl    = qkv3;
    bf16*  kpl    = qkv3 + (size_t)M * 256;
    bf16*  vpl    = qkv3 + (size_t)M * 512;
    bf16*  h1     = tln;   // [M][1024] bf16 = 102.76MB, spans tln+qkv3
    float* outf   = (float*)d_out;

    // 0+1+2. weight prep (+bias) AND posconv+LN1 in one launch
    pre_kernel<<<12544 + 3075, 256, 0, stream>>>(
        x, pos_w, pos_b, ln1_g, ln1_b, x1, tln,
        q_w, k_w, v_w, out_w, fc1_w, fc2_w, q_b, k_b, v_b,
        wt_qkv, wt_out, wt_fc1, wt_fc2, qkvb);

    // 3. q/k/v planes = tln @ [q|k*s|v] + bias  (196 m-tiles x 6 n-tiles)
    gemm_kernel<false, false, true, true><<<196 * 6, 512, 0, stream>>>(
        tln, wt_qkv, qkvb, nullptr, qkv3, M, 768, 256);
    // 4+5. width-axis attention AND lepe = dwconv5x5(v) in one launch
    attnw_lepe_kernel<<<1792 + 6272, 256, 0, stream>>>(
        qpl, kpl, vpl, mask_w, vwb, lepe_w, lepe_b, lepeb);
    // 6. height-axis attention (V = vw) + lepe -> obuf
    attnh_kernel<<<1792, 256, 0, stream>>>(qpl, kpl, vwb, mask_h, lepeb, obuf);
    // 7+8. x2 = x1 + obuf @ out_w + out_b -> d_out;  u = LN2(x2) -> lepeb (fused)
    outln_kernel<<<392, 512, 0, stream>>>(
        obuf, wt_out, out_b, x1, ln2_g, ln2_b, outf, lepeb);
    // 9. h1 = gelu(u @ fc1_w + fc1_b)  (196 x 8 tiles)
    gemm_kernel<true, false, true, false><<<196 * 8, 512, 0, stream>>>(
        lepeb, wt_fc1, fc1_b, nullptr, h1, M, 1024, 256);
    // 10. d_out = x2 + h1 @ fc2_w + fc2_b  (196 x 2 tiles)
    gemm_kernel<false, true, false, false><<<196 * 2, 512, 0, stream>>>(
        h1, wt_fc2, fc2_b, outf, outf, M, 256, 1024);
}

// Round 15
// 382.219 us; speedup vs baseline: 1.1365x; 1.1365x over previous
//
#include <hip/hip_runtime.h>
#include <hip/hip_bf16.h>
#include <math.h>
#include <stdint.h>

typedef __bf16 bf16;
typedef __bf16 bf16x8 __attribute__((ext_vector_type(8)));
typedef __bf16 bf16x4 __attribute__((ext_vector_type(4)));
typedef float f32x4 __attribute__((ext_vector_type(4)));

#define AS1 __attribute__((address_space(1)))
#define AS3 __attribute__((address_space(3)))

#define NPIX (16*56*56)          // 50176 pixels
#define CH 256
#define SCALE_K 0.17677669529663687f   // 32^-0.5

// gelu(tanh form) == vv * sigmoid(2u); exp2/rcp raw instructions.
__device__ __forceinline__ float gelu_fast(float vv) {
    float t = vv * (-2.30220781f + -0.10294330f * vv * vv);
    float e = __builtin_amdgcn_exp2f(t);
    return vv * __builtin_amdgcn_rcpf(1.0f + e);
}

// ------- fused: [0,12544) posconv+LN1 blocks; [12544,15619) weight prep --
// x1 stored bf16 (residual only; LN1 computed from fp32 regs).
__global__ __launch_bounds__(256) void pre_kernel(
    const float* __restrict__ x, const float* __restrict__ pos_w,
    const float* __restrict__ pos_b, const float* __restrict__ ln1_g,
    const float* __restrict__ ln1_b, bf16* __restrict__ x1,
    bf16* __restrict__ tln,
    const float* __restrict__ q_w, const float* __restrict__ k_w,
    const float* __restrict__ v_w, const float* __restrict__ out_w,
    const float* __restrict__ fc1_w, const float* __restrict__ fc2_w,
    const float* __restrict__ qb, const float* __restrict__ kb,
    const float* __restrict__ vb,
    bf16* __restrict__ wt_qkv, bf16* __restrict__ wt_out,
    bf16* __restrict__ wt_fc1, bf16* __restrict__ wt_fc2,
    float* __restrict__ qkvb)
{
    if (blockIdx.x >= 12544) {
        int idx = (blockIdx.x - 12544) * 256 + threadIdx.x;
        if (idx < 262144) {
            int w = idx >> 16;                 // 0=q 1=k 2=v 3=out
            int j = idx & 65535;
            int n = j >> 8, k = j & 255;
            const float* src = (w == 0) ? q_w : (w == 1) ? k_w : (w == 2) ? v_w : out_w;
            float scale = (w == 1) ? SCALE_K : 1.0f;
            bf16* dst = (w < 3) ? (wt_qkv + w * 65536) : wt_out;
            dst[j] = (bf16)(src[k * 256 + n] * scale);
        } else if (idx < 524288) {
            int j = idx - 262144;
            int n = j >> 8, k = j & 255;
            wt_fc1[j] = (bf16)(fc1_w[k * 1024 + n]);
        } else if (idx < 786432) {
            int j = idx - 524288;
            int n = j >> 10, k = j & 1023;
            wt_fc2[j] = (bf16)(fc2_w[k * 256 + n]);
        } else if (idx < 787200) {
            int i = idx - 786432;
            qkvb[i] = (i < 256) ? qb[i] : (i < 512) ? kb[i - 256] * SCALE_K : vb[i - 512];
        }
        return;
    }
    const int wave = threadIdx.x >> 6, lane = threadIdx.x & 63;
    const long pix = (long)blockIdx.x * 4 + wave;
    const int ww = (int)(pix % 56);
    const int hh = (int)((pix / 56) % 56);
    const int b  = (int)(pix / 3136);
    const int c  = lane * 4;
    float4 acc = ((const float4*)(pos_b + c))[0];
    float4 xin = ((const float4*)(x + pix * 256 + c))[0];
    acc.x += xin.x; acc.y += xin.y; acc.z += xin.z; acc.w += xin.w;
    #pragma unroll
    for (int dh = 0; dh < 3; ++dh) {
        int h2 = hh + dh - 1;
        if (h2 < 0 || h2 >= 56) continue;
        #pragma unroll
        for (int dw = 0; dw < 3; ++dw) {
            int w2 = ww + dw - 1;
            if (w2 < 0 || w2 >= 56) continue;
            float4 xv = ((const float4*)(x + (((long)(b * 56 + h2)) * 56 + w2) * 256 + c))[0];
            float4 wv = ((const float4*)(pos_w + (dh * 3 + dw) * 256 + c))[0];
            acc.x += xv.x * wv.x; acc.y += xv.y * wv.y;
            acc.z += xv.z * wv.z; acc.w += xv.w * wv.w;
        }
    }
    bf16* x1o = x1 + pix * 256 + c;
    x1o[0] = (bf16)acc.x; x1o[1] = (bf16)acc.y;
    x1o[2] = (bf16)acc.z; x1o[3] = (bf16)acc.w;
    float s  = acc.x + acc.y + acc.z + acc.w;
    float q2 = acc.x * acc.x + acc.y * acc.y + acc.z * acc.z + acc.w * acc.w;
    #pragma unroll
    for (int o = 32; o; o >>= 1) {
        s  += __shfl_xor(s,  o, 64);
        q2 += __shfl_xor(q2, o, 64);
    }
    float mean = s * (1.0f / 256.0f);
    float var  = q2 * (1.0f / 256.0f) - mean * mean;
    float rs   = rsqrtf(var + 1e-6f);
    float4 gv = ((const float4*)ln1_g)[lane];
    float4 bv = ((const float4*)ln1_b)[lane];
    bf16* o4 = tln + pix * 256 + c;
    o4[0] = (bf16)((acc.x - mean) * rs * gv.x + bv.x);
    o4[1] = (bf16)((acc.y - mean) * rs * gv.y + bv.y);
    o4[2] = (bf16)((acc.z - mean) * rs * gv.z + bv.z);
    o4[3] = (bf16)((acc.w - mean) * rs * gv.w + bv.w);
}

// ---------------- 5x5 depthwise conv on v plane ([M][256] bf16) ----------
__global__ __launch_bounds__(256) void lepe_kernel(
    const bf16* __restrict__ vpl, const float* __restrict__ w,
    const float* __restrict__ bias, bf16* __restrict__ out)
{
    long idx = (long)blockIdx.x * 256 + threadIdx.x;   // pix*32 + c8
    int c8 = (int)(idx & 31);
    long pix = idx >> 5;
    int ww = (int)(pix % 56);
    int hh = (int)((pix / 56) % 56);
    int b  = (int)(pix / 3136);
    int c  = c8 * 8;
    float acc[8];
    #pragma unroll
    for (int j = 0; j < 8; ++j) acc[j] = bias[c + j];
    #pragma unroll
    for (int dh = 0; dh < 5; ++dh) {
        int h2 = hh + dh - 2;
        if (h2 < 0 || h2 >= 56) continue;
        #pragma unroll
        for (int dw = 0; dw < 5; ++dw) {
            int w2 = ww + dw - 2;
            if (w2 < 0 || w2 >= 56) continue;
            bf16x8 vv = *(const bf16x8*)(vpl + (((long)(b * 56 + h2)) * 56 + w2) * 256 + c);
            const float4* wp = (const float4*)(w + (dh * 5 + dw) * 256 + c);
            float4 w0 = wp[0], w1 = wp[1];
            acc[0] += (float)vv[0] * w0.x; acc[1] += (float)vv[1] * w0.y;
            acc[2] += (float)vv[2] * w0.z; acc[3] += (float)vv[3] * w0.w;
            acc[4] += (float)vv[4] * w1.x; acc[5] += (float)vv[5] * w1.y;
            acc[6] += (float)vv[6] * w1.z; acc[7] += (float)vv[7] * w1.w;
        }
    }
    bf16* o = out + pix * 256 + c;
    #pragma unroll
    for (int j = 0; j < 8; ++j) o[j] = (bf16)acc[j];
}

// ---------------- MFMA attention: one wave per (b, line, head) task ------
template<bool WIDTH>
__global__ __launch_bounds__(256) void attn_mfma_kernel(
    const bf16* __restrict__ qp, const bf16* __restrict__ kp,
    const bf16* __restrict__ vsrc, const float* __restrict__ mask,
    const bf16* __restrict__ lepe, bf16* __restrict__ outp)
{
    __shared__ bf16 VtAll[4][32][72];   // V^T per wave: rows=d(32), cols=pos(64,swz)
    __shared__ bf16 PlAll[4][16][72];   // P per q-tile: rows=q_local(16), cols=kp(64)
    const int tid = threadIdx.x;
    const int wave = tid >> 6, lane = tid & 63;
    const int g = lane >> 4, ql = lane & 15;
    const int n  = blockIdx.x / 224;                  // head
    const int s  = (blockIdx.x % 224) * 4 + wave;     // slab: b*56 + line
    const int b  = s / 56, rc = s % 56;
    bf16 (*Vt)[72] = VtAll[wave];
    bf16 (*Pl)[72] = PlAll[wave];
    const long basePix = WIDTH ? ((long)(b * 56 + rc)) * 56 : (long)b * 3136 + rc;
    const long pixStride = WIDTH ? 1 : 56;
    const long stride = pixStride * 256;
    const bf16* qb = qp + basePix * 256 + n * 32;
    const bf16* kb = kp + basePix * 256 + n * 32;
    const bf16* vbp = vsrc + basePix * 256 + n * 32;

    #pragma unroll
    for (int it = 0; it < 2; ++it) {
        int idx = it * 64 + lane;
        if (idx < 112) {
            int pp = idx >> 2, chunk = idx & 3;
            int pos0 = pp * 2;
            bf16x8 v0 = *(const bf16x8*)(vbp + (long)pos0 * stride + chunk * 8);
            bf16x8 v1 = *(const bf16x8*)(vbp + (long)(pos0 + 1) * stride + chunk * 8);
            int colb = pos0 ^ (chunk << 3);
            #pragma unroll
            for (int j = 0; j < 8; ++j) {
                union { bf16 h[2]; unsigned int u; } pk;
                pk.h[0] = v0[j]; pk.h[1] = v1[j];
                *(unsigned int*)&Vt[chunk * 8 + j][colb] = pk.u;
            }
        }
    }
    if (lane < 32) {
        int d = lane;
        int colb = 56 ^ ((d >> 3) << 3);
        *(float4*)&Vt[d][colb] = (float4){0.f, 0.f, 0.f, 0.f};
    }

    bf16x8 qf[4], kf[4];
    #pragma unroll
    for (int t4 = 0; t4 < 4; ++t4) {
        int row = ql + 16 * t4; if (row > 55) row = 55;
        qf[t4] = *(const bf16x8*)(qb + (long)row * stride + 8 * g);
        kf[t4] = *(const bf16x8*)(kb + (long)row * stride + 8 * g);
    }

    f32x4 sA[4][4];
    __builtin_amdgcn_s_setprio(1);
    #pragma unroll
    for (int qt = 0; qt < 4; ++qt)
        #pragma unroll
        for (int kt = 0; kt < 4; ++kt)
            sA[qt][kt] = __builtin_amdgcn_mfma_f32_16x16x32_bf16(
                kf[kt], qf[qt], (f32x4){0.f, 0.f, 0.f, 0.f}, 0, 0, 0);
    __builtin_amdgcn_s_setprio(0);

    const float* mrow = mask + n * 3136;
    #pragma unroll
    for (int qt = 0; qt < 4; ++qt) {
        int qm = ql + 16 * qt; if (qm > 55) qm = 55;
        #pragma unroll
        for (int kt = 0; kt < 4; ++kt) {
            if (kt == 3 && g >= 2) {
                sA[qt][3][0] = -3.0e38f; sA[qt][3][1] = -3.0e38f;
                sA[qt][3][2] = -3.0e38f; sA[qt][3][3] = -3.0e38f;
            } else {
                float4 mv = *(const float4*)(mrow + qm * 56 + kt * 16 + 4 * g);
                sA[qt][kt][0] += mv.x; sA[qt][kt][1] += mv.y;
                sA[qt][kt][2] += mv.z; sA[qt][kt][3] += mv.w;
            }
        }
    }

    #pragma unroll
    for (int qt = 0; qt < 4; ++qt) {
        float m = -3.0e38f;
        #pragma unroll
        for (int kt = 0; kt < 4; ++kt)
            #pragma unroll
            for (int r = 0; r < 4; ++r) m = fmaxf(m, sA[qt][kt][r]);
        m = fmaxf(m, __shfl_xor(m, 16, 64));
        m = fmaxf(m, __shfl_xor(m, 32, 64));
        float p[4][4];
        float sum = 0.f;
        #pragma unroll
        for (int kt = 0; kt < 4; ++kt)
            #pragma unroll
            for (int r = 0; r < 4; ++r) {
                float e = exp2f((sA[qt][kt][r] - m) * 1.4426950408889634f);
                p[kt][r] = e; sum += e;
            }
        sum += __shfl_xor(sum, 16, 64);
        sum += __shfl_xor(sum, 32, 64);
        float rinv = 1.0f / sum;
        #pragma unroll
        for (int kt = 0; kt < 4; ++kt) {
            bf16x4 w;
            #pragma unroll
            for (int r = 0; r < 4; ++r) w[r] = (bf16)(p[kt][r] * rinv);
            *(bf16x4*)&Pl[ql][kt * 16 + 4 * g] = w;
        }
        #pragma unroll
        for (int nt = 0; nt < 2; ++nt) {
            f32x4 o = {0.f, 0.f, 0.f, 0.f};
            __builtin_amdgcn_s_setprio(1);
            #pragma unroll
            for (int ks = 0; ks < 2; ++ks) {
                bf16x8 af = *(const bf16x8*)&Pl[ql][ks * 32 + 8 * g];
                int vrow = ql + 16 * nt;
                int vcol = (ks * 32 + 8 * g) ^ ((vrow >> 3) << 3);
                bf16x8 bv = *(const bf16x8*)&Vt[vrow][vcol];
                o = __builtin_amdgcn_mfma_f32_16x16x32_bf16(af, bv, o, 0, 0, 0);
            }
            __builtin_amdgcn_s_setprio(0);
            if (!(qt == 3 && g >= 2)) {
                #pragma unroll
                for (int r = 0; r < 4; ++r) {
                    int q = 16 * qt + 4 * g + r;
                    long addr = (basePix + (long)q * pixStride) * 256 + n * 32 + nt * 16 + ql;
                    float vv = o[r];
                    if (!WIDTH) vv += (float)lepe[addr];
                    outp[addr] = (bf16)vv;
                }
            }
        }
    }
}

// ---------------- bf16 MFMA GEMM: 256x128 tile, 8 waves (4M x 2N) --------
// resid is bf16 (fc2's x2 trunk).
template<bool GELU, bool RESID, bool OUT_BF16, bool QKV3>
__global__ __launch_bounds__(512) void gemm_kernel(
    const bf16* __restrict__ A, const bf16* __restrict__ Wt,
    const float* __restrict__ bias, const bf16* __restrict__ resid,
    void* __restrict__ Cout, int M, int N, int K)
{
    __shared__ bf16 As[256 * 64];
    __shared__ bf16 Bs[128 * 64];
    const int t = threadIdx.x;
    const int wave = t >> 6, lane = t & 63;
    const int nTilesN = N >> 7;
    const int q8 = gridDim.x >> 3;                    // T1 swizzle (grid % 8 == 0)
    const int o = ((int)blockIdx.x & 7) * q8 + ((int)blockIdx.x >> 3);
    const int tm = o / nTilesN, tn = o % nTilesN;
    const long m0 = (long)tm * 256, n0 = (long)tn * 128;
    const int waveM = (wave >> 1) * 64, waveN = (wave & 1) * 64;
    f32x4 acc[4][4] = {};

    for (int k0 = 0; k0 < K; k0 += 64) {
        #pragma unroll
        for (int i = 0; i < 4; ++i) {                 // A: 2048 chunks of 16B
            int c = i * 512 + t;
            int r = c >> 3, cc = (c & 7) * 8;
            const bf16* ga = A + (m0 + r) * (long)K + k0 + cc;
            __builtin_amdgcn_global_load_lds(
                (const AS1 void*)ga, (AS3 void*)(As + c * 8), 16, 0, 0);
        }
        #pragma unroll
        for (int i = 0; i < 2; ++i) {                 // B: 1024 chunks of 16B
            int c = i * 512 + t;
            int r = c >> 3, cc = (c & 7) * 8;
            const bf16* gb = Wt + (n0 + r) * (long)K + k0 + cc;
            __builtin_amdgcn_global_load_lds(
                (const AS1 void*)gb, (AS3 void*)(Bs + c * 8), 16, 0, 0);
        }
        __syncthreads();
        #pragma unroll
        for (int kk = 0; kk < 2; ++kk) {
            bf16x8 af[4], bfr[4];
            const int krow = kk * 32 + (lane >> 4) * 8;
            #pragma unroll
            for (int fm = 0; fm < 4; ++fm)
                af[fm] = *(const bf16x8*)&As[(waveM + fm * 16 + (lane & 15)) * 64 + krow];
            #pragma unroll
            for (int fn = 0; fn < 4; ++fn)
                bfr[fn] = *(const bf16x8*)&Bs[(waveN + fn * 16 + (lane & 15)) * 64 + krow];
            #pragma unroll
            for (int fm = 0; fm < 4; ++fm)
                #pragma unroll
                for (int fn = 0; fn < 4; ++fn)
                    acc[fm][fn] = __builtin_amdgcn_mfma_f32_16x16x32_bf16(
                        af[fm], bfr[fn], acc[fm][fn], 0, 0, 0);
        }
        __syncthreads();
    }

    #pragma unroll
    for (int fm = 0; fm < 4; ++fm) {
        #pragma unroll
        for (int r = 0; r < 4; ++r) {
            const long m = m0 + waveM + fm * 16 + (lane >> 4) * 4 + r;
            #pragma unroll
            for (int fn = 0; fn < 4; ++fn) {
                const long n = n0 + waveN + fn * 16 + (lane & 15);
                float vv = acc[fm][fn][r] + bias[n];
                if (GELU)  vv = gelu_fast(vv);
                if (RESID) vv += (float)resid[m * N + n];
                if (QKV3) {
                    long pl = n >> 8;
                    ((bf16*)Cout)[pl * (long)NPIX * 256 + m * 256 + (n & 255)] = (bf16)vv;
                } else if (OUT_BF16) {
                    ((bf16*)Cout)[m * N + n] = (bf16)vv;
                } else {
                    ((float*)Cout)[m * N + n] = vv;
                }
            }
        }
    }
}

// ------- fused out-proj GEMM + residual(bf16) + LayerNorm2 --------------
// x2 trunk stored bf16 (LN2 computed from fp32 regs; fc2 re-reads bf16).
__global__ __launch_bounds__(512) void outln_kernel(
    const bf16* __restrict__ A, const bf16* __restrict__ Wt,
    const float* __restrict__ bias, const bf16* __restrict__ resid,
    const float* __restrict__ g2, const float* __restrict__ b2,
    bf16* __restrict__ x2out, bf16* __restrict__ uout)
{
    __shared__ bf16 As[128 * 64];
    __shared__ bf16 Bs[256 * 64];
    const int t = threadIdx.x;
    const int wave = t >> 6, lane = t & 63;
    const int g = lane >> 4, ql = lane & 15;
    const int q8 = gridDim.x >> 3;
    const int o = ((int)blockIdx.x & 7) * q8 + ((int)blockIdx.x >> 3);
    const long m0 = (long)o * 128;
    const int waveM = wave * 16;
    f32x4 acc[16] = {};

    for (int k0 = 0; k0 < 256; k0 += 64) {
        #pragma unroll
        for (int i = 0; i < 2; ++i) {                 // A: 1024 chunks
            int c = i * 512 + t;
            int r = c >> 3, cc = (c & 7) * 8;
            const bf16* ga = A + (m0 + r) * 256 + k0 + cc;
            __builtin_amdgcn_global_load_lds(
                (const AS1 void*)ga, (AS3 void*)(As + c * 8), 16, 0, 0);
        }
        #pragma unroll
        for (int i = 0; i < 4; ++i) {                 // B: 2048 chunks
            int c = i * 512 + t;
            int r = c >> 3, cc = (c & 7) * 8;
            const bf16* gb = Wt + r * 256 + k0 + cc;
            __builtin_amdgcn_global_load_lds(
                (const AS1 void*)gb, (AS3 void*)(Bs + c * 8), 16, 0, 0);
        }
        __syncthreads();
        #pragma unroll
        for (int kk = 0; kk < 2; ++kk) {
            const int krow = kk * 32 + g * 8;
            bf16x8 af = *(const bf16x8*)&As[(waveM + ql) * 64 + krow];
            #pragma unroll
            for (int fn = 0; fn < 16; ++fn) {
                bf16x8 bv = *(const bf16x8*)&Bs[(fn * 16 + ql) * 64 + krow];
                acc[fn] = __builtin_amdgcn_mfma_f32_16x16x32_bf16(af, bv, acc[fn], 0, 0, 0);
            }
        }
        __syncthreads();
    }

    float rsum[4] = {}, rsq[4] = {};
    #pragma unroll
    for (int fn = 0; fn < 16; ++fn) {
        const int n = fn * 16 + ql;
        const float bn = bias[n];
        #pragma unroll
        for (int r = 0; r < 4; ++r) {
            const long m = m0 + waveM + g * 4 + r;
            float v = acc[fn][r] + bn + (float)resid[m * 256 + n];
            acc[fn][r] = v;
            rsum[r] += v; rsq[r] += v * v;
        }
    }
    #pragma unroll
    for (int r = 0; r < 4; ++r) {
        float s = rsum[r], q = rsq[r];
        #pragma unroll
        for (int off = 8; off; off >>= 1) {
            s += __shfl_xor(s, off, 64);
            q += __shfl_xor(q, off, 64);
        }
        float mean = s * (1.0f / 256.0f);
        float var  = q * (1.0f / 256.0f) - mean * mean;
        rsum[r] = mean;
        rsq[r]  = rsqrtf(var + 1e-6f);
    }
    #pragma unroll
    for (int fn = 0; fn < 16; ++fn) {
        const int n = fn * 16 + ql;
        const float gn = g2[n], bn2 = b2[n];
        #pragma unroll
        for (int r = 0; r < 4; ++r) {
            const long m = m0 + waveM + g * 4 + r;
            float v = acc[fn][r];
            x2out[m * 256 + n] = (bf16)v;
            uout[m * 256 + n] = (bf16)((v - rsum[r]) * rsq[r] * gn + bn2);
        }
    }
}

// ------------------------------- launch ----------------------------------
extern "C" void kernel_launch(void* const* d_in, const int* in_sizes, int n_in,
                              void* d_out, int out_size, void* d_ws, size_t ws_size,
                              hipStream_t stream)
{
    (void)in_sizes; (void)n_in; (void)out_size; (void)ws_size;
    const float* x      = (const float*)d_in[0];
    const float* mask_h = (const float*)d_in[1];
    const float* mask_w = (const float*)d_in[2];
    const float* pos_w  = (const float*)d_in[3];
    const float* pos_b  = (const float*)d_in[4];
    const float* ln1_g  = (const float*)d_in[5];
    const float* ln1_b  = (const float*)d_in[6];
    const float* q_w    = (const float*)d_in[7];
    const float* q_b    = (const float*)d_in[8];
    const float* k_w    = (const float*)d_in[9];
    const float* k_b    = (const float*)d_in[10];
    const float* v_w    = (const float*)d_in[11];
    const float* v_b    = (const float*)d_in[12];
    const float* lepe_w = (const float*)d_in[13];
    const float* lepe_b = (const float*)d_in[14];
    const float* out_w  = (const float*)d_in[15];
    const float* out_b  = (const float*)d_in[16];
    const float* ln2_g  = (const float*)d_in[17];
    const float* ln2_b  = (const float*)d_in[18];
    const float* fc1_w  = (const float*)d_in[19];
    const float* fc1_b  = (const float*)d_in[20];
    const float* fc2_w  = (const float*)d_in[21];
    const float* fc2_b  = (const float*)d_in[22];

    char* ws = (char*)d_ws;
    size_t off = 0;
    auto alloc = [&](size_t bytes) -> void* {
        void* p = ws + off;
        off += (bytes + 255) & ~(size_t)255;
        return p;
    };
    const int M = NPIX;
    bf16*  x1     = (bf16*) alloc((size_t)M * 256 * 2);       // x + posconv (bf16 residual)
    bf16*  tln    = (bf16*) alloc((size_t)M * 256 * 2);       // LN1 out
    bf16*  qkv3   = (bf16*) alloc((size_t)M * 768 * 2);       // q|k|v PLANAR (3x M*256)
    bf16*  lepeb  = (bf16*) alloc((size_t)M * 256 * 2);       // lepe; later reused as LN2 out
    bf16*  vwb    = (bf16*) alloc((size_t)M * 256 * 2);       // width-attention output
    bf16*  obuf   = (bf16*) alloc((size_t)M * 256 * 2);       // height-attn out + lepe
    bf16*  x2b    = (bf16*) alloc((size_t)M * 256 * 2);       // x2 trunk (bf16)
    bf16*  wt_qkv = (bf16*) alloc((size_t)768 * 256 * 2);
    bf16*  wt_out = (bf16*) alloc((size_t)256 * 256 * 2);
    bf16*  wt_fc1 = (bf16*) alloc((size_t)1024 * 256 * 2);
    bf16*  wt_fc2 = (bf16*) alloc((size_t)256 * 1024 * 2);
    float* qkvb   = (float*)alloc(768 * 4);
    bf16*  qpl    = qkv3;
    bf16*  kpl    = qkv3 + (size_t)M * 256;
    bf16*  vpl    = qkv3 + (size_t)M * 512;
    bf16*  h1     = tln;   // [M][1024] bf16 = 102.76MB, spans tln+qkv3
    float* outf   = (float*)d_out;

    // 0+1+2. weight prep (+bias) AND posconv+LN1 in one launch
    pre_kernel<<<12544 + 3075, 256, 0, stream>>>(
        x, pos_w, pos_b, ln1_g, ln1_b, x1, tln,
        q_w, k_w, v_w, out_w, fc1_w, fc2_w, q_b, k_b, v_b,
        wt_qkv, wt_out, wt_fc1, wt_fc2, qkvb);

    // 3. q/k/v planes = tln @ [q|k*s|v] + bias  (196 m-tiles x 6 n-tiles)
    gemm_kernel<false, false, true, true><<<196 * 6, 512, 0, stream>>>(
        tln, wt_qkv, qkvb, nullptr, qkv3, M, 768, 256);
    // 4. lepe = dwconv5x5(v)
    lepe_kernel<<<6272, 256, 0, stream>>>(vpl, lepe_w, lepe_b, lepeb);
    // 5. width-axis attention -> vw
    attn_mfma_kernel<true><<<1792, 256, 0, stream>>>(qpl, kpl, vpl, mask_w, nullptr, vwb);
    // 6. height-axis attention (V = vw) + lepe -> obuf
    attn_mfma_kernel<false><<<1792, 256, 0, stream>>>(qpl, kpl, vwb, mask_h, lepeb, obuf);
    // 7+8. x2 = x1 + obuf @ out_w + out_b -> x2b (bf16);  u = LN2(x2) -> lepeb
    outln_kernel<<<392, 512, 0, stream>>>(
        obuf, wt_out, out_b, x1, ln2_g, ln2_b, x2b, lepeb);
    // 9. h1 = gelu(u @ fc1_w + fc1_b)  (196 x 8 tiles)
    gemm_kernel<true, false, true, false><<<196 * 8, 512, 0, stream>>>(
        lepeb, wt_fc1, fc1_b, nullptr, h1, M, 1024, 256);
    // 10. d_out = x2 + h1 @ fc2_w + fc2_b  (196 x 2 tiles, fp32 out)
    gemm_kernel<false, true, false, false><<<196 * 2, 512, 0, stream>>>(
        h1, wt_fc2, fc2_b, x2b, outf, M, 256, 1024);
}

// Round 16
// 380.260 us; speedup vs baseline: 1.1424x; 1.0052x over previous
//
#include <hip/hip_runtime.h>
#include <hip/hip_bf16.h>
#include <math.h>
#include <stdint.h>

typedef __bf16 bf16;
typedef __bf16 bf16x8 __attribute__((ext_vector_type(8)));
typedef __bf16 bf16x4 __attribute__((ext_vector_type(4)));
typedef float f32x4 __attribute__((ext_vector_type(4)));

#define AS1 __attribute__((address_space(1)))
#define AS3 __attribute__((address_space(3)))

#define NPIX (16*56*56)          // 50176 pixels
#define CH 256
#define SCALE_K 0.17677669529663687f   // 32^-0.5

// gelu(tanh form) == vv * sigmoid(2u); exp2/rcp raw instructions.
__device__ __forceinline__ float gelu_fast(float vv) {
    float t = vv * (-2.30220781f + -0.10294330f * vv * vv);
    float e = __builtin_amdgcn_exp2f(t);
    return vv * __builtin_amdgcn_rcpf(1.0f + e);
}

// ------- fused: [0,12544) posconv+LN1 blocks; [12544,15619) weight prep --
// x1 stored bf16 (residual only; LN1 computed from fp32 regs).
__global__ __launch_bounds__(256) void pre_kernel(
    const float* __restrict__ x, const float* __restrict__ pos_w,
    const float* __restrict__ pos_b, const float* __restrict__ ln1_g,
    const float* __restrict__ ln1_b, bf16* __restrict__ x1,
    bf16* __restrict__ tln,
    const float* __restrict__ q_w, const float* __restrict__ k_w,
    const float* __restrict__ v_w, const float* __restrict__ out_w,
    const float* __restrict__ fc1_w, const float* __restrict__ fc2_w,
    const float* __restrict__ qb, const float* __restrict__ kb,
    const float* __restrict__ vb,
    bf16* __restrict__ wt_qkv, bf16* __restrict__ wt_out,
    bf16* __restrict__ wt_fc1, bf16* __restrict__ wt_fc2,
    float* __restrict__ qkvb)
{
    if (blockIdx.x >= 12544) {
        int idx = (blockIdx.x - 12544) * 256 + threadIdx.x;
        if (idx < 262144) {
            int w = idx >> 16;                 // 0=q 1=k 2=v 3=out
            int j = idx & 65535;
            int n = j >> 8, k = j & 255;
            const float* src = (w == 0) ? q_w : (w == 1) ? k_w : (w == 2) ? v_w : out_w;
            float scale = (w == 1) ? SCALE_K : 1.0f;
            bf16* dst = (w < 3) ? (wt_qkv + w * 65536) : wt_out;
            dst[j] = (bf16)(src[k * 256 + n] * scale);
        } else if (idx < 524288) {
            int j = idx - 262144;
            int n = j >> 8, k = j & 255;
            wt_fc1[j] = (bf16)(fc1_w[k * 1024 + n]);
        } else if (idx < 786432) {
            int j = idx - 524288;
            int n = j >> 10, k = j & 1023;
            wt_fc2[j] = (bf16)(fc2_w[k * 256 + n]);
        } else if (idx < 787200) {
            int i = idx - 786432;
            qkvb[i] = (i < 256) ? qb[i] : (i < 512) ? kb[i - 256] * SCALE_K : vb[i - 512];
        }
        return;
    }
    const int wave = threadIdx.x >> 6, lane = threadIdx.x & 63;
    const long pix = (long)blockIdx.x * 4 + wave;
    const int ww = (int)(pix % 56);
    const int hh = (int)((pix / 56) % 56);
    const int b  = (int)(pix / 3136);
    const int c  = lane * 4;
    float4 acc = ((const float4*)(pos_b + c))[0];
    float4 xin = ((const float4*)(x + pix * 256 + c))[0];
    acc.x += xin.x; acc.y += xin.y; acc.z += xin.z; acc.w += xin.w;
    #pragma unroll
    for (int dh = 0; dh < 3; ++dh) {
        int h2 = hh + dh - 1;
        if (h2 < 0 || h2 >= 56) continue;
        #pragma unroll
        for (int dw = 0; dw < 3; ++dw) {
            int w2 = ww + dw - 1;
            if (w2 < 0 || w2 >= 56) continue;
            float4 xv = ((const float4*)(x + (((long)(b * 56 + h2)) * 56 + w2) * 256 + c))[0];
            float4 wv = ((const float4*)(pos_w + (dh * 3 + dw) * 256 + c))[0];
            acc.x += xv.x * wv.x; acc.y += xv.y * wv.y;
            acc.z += xv.z * wv.z; acc.w += xv.w * wv.w;
        }
    }
    bf16* x1o = x1 + pix * 256 + c;
    x1o[0] = (bf16)acc.x; x1o[1] = (bf16)acc.y;
    x1o[2] = (bf16)acc.z; x1o[3] = (bf16)acc.w;
    float s  = acc.x + acc.y + acc.z + acc.w;
    float q2 = acc.x * acc.x + acc.y * acc.y + acc.z * acc.z + acc.w * acc.w;
    #pragma unroll
    for (int o = 32; o; o >>= 1) {
        s  += __shfl_xor(s,  o, 64);
        q2 += __shfl_xor(q2, o, 64);
    }
    float mean = s * (1.0f / 256.0f);
    float var  = q2 * (1.0f / 256.0f) - mean * mean;
    float rs   = rsqrtf(var + 1e-6f);
    float4 gv = ((const float4*)ln1_g)[lane];
    float4 bv = ((const float4*)ln1_b)[lane];
    bf16* o4 = tln + pix * 256 + c;
    o4[0] = (bf16)((acc.x - mean) * rs * gv.x + bv.x);
    o4[1] = (bf16)((acc.y - mean) * rs * gv.y + bv.y);
    o4[2] = (bf16)((acc.z - mean) * rs * gv.z + bv.z);
    o4[3] = (bf16)((acc.w - mean) * rs * gv.w + bv.w);
}

// ------- 5x5 depthwise conv, register-blocked: 4-pixel column per thread -
// Thread = (b, w, h-group of 4, 8-channel group). Loads 8 rows x 5 cols
// (10 loads/output vs 25); dh = rr - o is compile-time after unroll.
__global__ __launch_bounds__(256) void lepe_kernel(
    const bf16* __restrict__ vpl, const float* __restrict__ w,
    const float* __restrict__ bias, bf16* __restrict__ out)
{
    long idx = (long)blockIdx.x * 256 + threadIdx.x;   // task*32 + c8
    int c8 = (int)(idx & 31);
    long task = idx >> 5;                              // 12544 tasks
    int hg = (int)(task % 14);
    int ww = (int)((task / 14) % 56);
    int b  = (int)(task / (14 * 56));
    int c  = c8 * 8;
    int h0 = hg * 4;
    float acc[4][8];
    #pragma unroll
    for (int o = 0; o < 4; ++o)
        #pragma unroll
        for (int j = 0; j < 8; ++j) acc[o][j] = bias[c + j];

    #pragma unroll
    for (int rr = 0; rr < 8; ++rr) {
        int h2 = h0 - 2 + rr;
        if (h2 < 0 || h2 >= 56) continue;
        #pragma unroll
        for (int dw = 0; dw < 5; ++dw) {
            int w2 = ww + dw - 2;
            if (w2 < 0 || w2 >= 56) continue;
            bf16x8 vv = *(const bf16x8*)(vpl + (((long)(b * 56 + h2)) * 56 + w2) * 256 + c);
            float f[8];
            #pragma unroll
            for (int j = 0; j < 8; ++j) f[j] = (float)vv[j];
            #pragma unroll
            for (int o = 0; o < 4; ++o) {
                int dh = rr - o;                       // compile-time per (rr,o)
                if (dh < 0 || dh > 4) continue;
                const float4* wp = (const float4*)(w + (dh * 5 + dw) * 256 + c);
                float4 w0 = wp[0], w1 = wp[1];
                acc[o][0] += f[0] * w0.x; acc[o][1] += f[1] * w0.y;
                acc[o][2] += f[2] * w0.z; acc[o][3] += f[3] * w0.w;
                acc[o][4] += f[4] * w1.x; acc[o][5] += f[5] * w1.y;
                acc[o][6] += f[6] * w1.z; acc[o][7] += f[7] * w1.w;
            }
        }
    }
    #pragma unroll
    for (int o = 0; o < 4; ++o) {
        long pix = ((long)(b * 56 + h0 + o)) * 56 + ww;
        bf16* op = out + pix * 256 + c;
        #pragma unroll
        for (int j = 0; j < 8; ++j) op[j] = (bf16)acc[o][j];
    }
}

// ---------------- MFMA attention: one wave per (b, line, head) task ------
template<bool WIDTH>
__global__ __launch_bounds__(256) void attn_mfma_kernel(
    const bf16* __restrict__ qp, const bf16* __restrict__ kp,
    const bf16* __restrict__ vsrc, const float* __restrict__ mask,
    const bf16* __restrict__ lepe, bf16* __restrict__ outp)
{
    __shared__ bf16 VtAll[4][32][72];   // V^T per wave: rows=d(32), cols=pos(64,swz)
    __shared__ bf16 PlAll[4][16][72];   // P per q-tile: rows=q_local(16), cols=kp(64)
    const int tid = threadIdx.x;
    const int wave = tid >> 6, lane = tid & 63;
    const int g = lane >> 4, ql = lane & 15;
    const int n  = blockIdx.x / 224;                  // head
    const int s  = (blockIdx.x % 224) * 4 + wave;     // slab: b*56 + line
    const int b  = s / 56, rc = s % 56;
    bf16 (*Vt)[72] = VtAll[wave];
    bf16 (*Pl)[72] = PlAll[wave];
    const long basePix = WIDTH ? ((long)(b * 56 + rc)) * 56 : (long)b * 3136 + rc;
    const long pixStride = WIDTH ? 1 : 56;
    const long stride = pixStride * 256;
    const bf16* qb = qp + basePix * 256 + n * 32;
    const bf16* kb = kp + basePix * 256 + n * 32;
    const bf16* vbp = vsrc + basePix * 256 + n * 32;

    #pragma unroll
    for (int it = 0; it < 2; ++it) {
        int idx = it * 64 + lane;
        if (idx < 112) {
            int pp = idx >> 2, chunk = idx & 3;
            int pos0 = pp * 2;
            bf16x8 v0 = *(const bf16x8*)(vbp + (long)pos0 * stride + chunk * 8);
            bf16x8 v1 = *(const bf16x8*)(vbp + (long)(pos0 + 1) * stride + chunk * 8);
            int colb = pos0 ^ (chunk << 3);
            #pragma unroll
            for (int j = 0; j < 8; ++j) {
                union { bf16 h[2]; unsigned int u; } pk;
                pk.h[0] = v0[j]; pk.h[1] = v1[j];
                *(unsigned int*)&Vt[chunk * 8 + j][colb] = pk.u;
            }
        }
    }
    if (lane < 32) {
        int d = lane;
        int colb = 56 ^ ((d >> 3) << 3);
        *(float4*)&Vt[d][colb] = (float4){0.f, 0.f, 0.f, 0.f};
    }

    bf16x8 qf[4], kf[4];
    #pragma unroll
    for (int t4 = 0; t4 < 4; ++t4) {
        int row = ql + 16 * t4; if (row > 55) row = 55;
        qf[t4] = *(const bf16x8*)(qb + (long)row * stride + 8 * g);
        kf[t4] = *(const bf16x8*)(kb + (long)row * stride + 8 * g);
    }

    f32x4 sA[4][4];
    __builtin_amdgcn_s_setprio(1);
    #pragma unroll
    for (int qt = 0; qt < 4; ++qt)
        #pragma unroll
        for (int kt = 0; kt < 4; ++kt)
            sA[qt][kt] = __builtin_amdgcn_mfma_f32_16x16x32_bf16(
                kf[kt], qf[qt], (f32x4){0.f, 0.f, 0.f, 0.f}, 0, 0, 0);
    __builtin_amdgcn_s_setprio(0);

    const float* mrow = mask + n * 3136;
    #pragma unroll
    for (int qt = 0; qt < 4; ++qt) {
        int qm = ql + 16 * qt; if (qm > 55) qm = 55;
        #pragma unroll
        for (int kt = 0; kt < 4; ++kt) {
            if (kt == 3 && g >= 2) {
                sA[qt][3][0] = -3.0e38f; sA[qt][3][1] = -3.0e38f;
                sA[qt][3][2] = -3.0e38f; sA[qt][3][3] = -3.0e38f;
            } else {
                float4 mv = *(const float4*)(mrow + qm * 56 + kt * 16 + 4 * g);
                sA[qt][kt][0] += mv.x; sA[qt][kt][1] += mv.y;
                sA[qt][kt][2] += mv.z; sA[qt][kt][3] += mv.w;
            }
        }
    }

    #pragma unroll
    for (int qt = 0; qt < 4; ++qt) {
        float m = -3.0e38f;
        #pragma unroll
        for (int kt = 0; kt < 4; ++kt)
            #pragma unroll
            for (int r = 0; r < 4; ++r) m = fmaxf(m, sA[qt][kt][r]);
        m = fmaxf(m, __shfl_xor(m, 16, 64));
        m = fmaxf(m, __shfl_xor(m, 32, 64));
        float p[4][4];
        float sum = 0.f;
        #pragma unroll
        for (int kt = 0; kt < 4; ++kt)
            #pragma unroll
            for (int r = 0; r < 4; ++r) {
                float e = exp2f((sA[qt][kt][r] - m) * 1.4426950408889634f);
                p[kt][r] = e; sum += e;
            }
        sum += __shfl_xor(sum, 16, 64);
        sum += __shfl_xor(sum, 32, 64);
        float rinv = 1.0f / sum;
        #pragma unroll
        for (int kt = 0; kt < 4; ++kt) {
            bf16x4 w;
            #pragma unroll
            for (int r = 0; r < 4; ++r) w[r] = (bf16)(p[kt][r] * rinv);
            *(bf16x4*)&Pl[ql][kt * 16 + 4 * g] = w;
        }
        #pragma unroll
        for (int nt = 0; nt < 2; ++nt) {
            f32x4 o = {0.f, 0.f, 0.f, 0.f};
            __builtin_amdgcn_s_setprio(1);
            #pragma unroll
            for (int ks = 0; ks < 2; ++ks) {
                bf16x8 af = *(const bf16x8*)&Pl[ql][ks * 32 + 8 * g];
                int vrow = ql + 16 * nt;
                int vcol = (ks * 32 + 8 * g) ^ ((vrow >> 3) << 3);
                bf16x8 bv = *(const bf16x8*)&Vt[vrow][vcol];
                o = __builtin_amdgcn_mfma_f32_16x16x32_bf16(af, bv, o, 0, 0, 0);
            }
            __builtin_amdgcn_s_setprio(0);
            if (!(qt == 3 && g >= 2)) {
                #pragma unroll
                for (int r = 0; r < 4; ++r) {
                    int q = 16 * qt + 4 * g + r;
                    long addr = (basePix + (long)q * pixStride) * 256 + n * 32 + nt * 16 + ql;
                    float vv = o[r];
                    if (!WIDTH) vv += (float)lepe[addr];
                    outp[addr] = (bf16)vv;
                }
            }
        }
    }
}

// ---------------- bf16 MFMA GEMM: 256x128 tile, 8 waves (4M x 2N) --------
// resid is bf16 (fc2's x2 trunk).
template<bool GELU, bool RESID, bool OUT_BF16, bool QKV3>
__global__ __launch_bounds__(512) void gemm_kernel(
    const bf16* __restrict__ A, const bf16* __restrict__ Wt,
    const float* __restrict__ bias, const bf16* __restrict__ resid,
    void* __restrict__ Cout, int M, int N, int K)
{
    __shared__ bf16 As[256 * 64];
    __shared__ bf16 Bs[128 * 64];
    const int t = threadIdx.x;
    const int wave = t >> 6, lane = t & 63;
    const int nTilesN = N >> 7;
    const int q8 = gridDim.x >> 3;                    // T1 swizzle (grid % 8 == 0)
    const int o = ((int)blockIdx.x & 7) * q8 + ((int)blockIdx.x >> 3);
    const int tm = o / nTilesN, tn = o % nTilesN;
    const long m0 = (long)tm * 256, n0 = (long)tn * 128;
    const int waveM = (wave >> 1) * 64, waveN = (wave & 1) * 64;
    f32x4 acc[4][4] = {};

    for (int k0 = 0; k0 < K; k0 += 64) {
        #pragma unroll
        for (int i = 0; i < 4; ++i) {                 // A: 2048 chunks of 16B
            int c = i * 512 + t;
            int r = c >> 3, cc = (c & 7) * 8;
            const bf16* ga = A + (m0 + r) * (long)K + k0 + cc;
            __builtin_amdgcn_global_load_lds(
                (const AS1 void*)ga, (AS3 void*)(As + c * 8), 16, 0, 0);
        }
        #pragma unroll
        for (int i = 0; i < 2; ++i) {                 // B: 1024 chunks of 16B
            int c = i * 512 + t;
            int r = c >> 3, cc = (c & 7) * 8;
            const bf16* gb = Wt + (n0 + r) * (long)K + k0 + cc;
            __builtin_amdgcn_global_load_lds(
                (const AS1 void*)gb, (AS3 void*)(Bs + c * 8), 16, 0, 0);
        }
        __syncthreads();
        #pragma unroll
        for (int kk = 0; kk < 2; ++kk) {
            bf16x8 af[4], bfr[4];
            const int krow = kk * 32 + (lane >> 4) * 8;
            #pragma unroll
            for (int fm = 0; fm < 4; ++fm)
                af[fm] = *(const bf16x8*)&As[(waveM + fm * 16 + (lane & 15)) * 64 + krow];
            #pragma unroll
            for (int fn = 0; fn < 4; ++fn)
                bfr[fn] = *(const bf16x8*)&Bs[(waveN + fn * 16 + (lane & 15)) * 64 + krow];
            #pragma unroll
            for (int fm = 0; fm < 4; ++fm)
                #pragma unroll
                for (int fn = 0; fn < 4; ++fn)
                    acc[fm][fn] = __builtin_amdgcn_mfma_f32_16x16x32_bf16(
                        af[fm], bfr[fn], acc[fm][fn], 0, 0, 0);
        }
        __syncthreads();
    }

    #pragma unroll
    for (int fm = 0; fm < 4; ++fm) {
        #pragma unroll
        for (int r = 0; r < 4; ++r) {
            const long m = m0 + waveM + fm * 16 + (lane >> 4) * 4 + r;
            #pragma unroll
            for (int fn = 0; fn < 4; ++fn) {
                const long n = n0 + waveN + fn * 16 + (lane & 15);
                float vv = acc[fm][fn][r] + bias[n];
                if (GELU)  vv = gelu_fast(vv);
                if (RESID) vv += (float)resid[m * N + n];
                if (QKV3) {
                    long pl = n >> 8;
                    ((bf16*)Cout)[pl * (long)NPIX * 256 + m * 256 + (n & 255)] = (bf16)vv;
                } else if (OUT_BF16) {
                    ((bf16*)Cout)[m * N + n] = (bf16)vv;
                } else {
                    ((float*)Cout)[m * N + n] = vv;
                }
            }
        }
    }
}

// ------- fused out-proj GEMM + residual(bf16) + LayerNorm2 --------------
// x2 trunk stored bf16 (LN2 computed from fp32 regs; fc2 re-reads bf16).
__global__ __launch_bounds__(512) void outln_kernel(
    const bf16* __restrict__ A, const bf16* __restrict__ Wt,
    const float* __restrict__ bias, const bf16* __restrict__ resid,
    const float* __restrict__ g2, const float* __restrict__ b2,
    bf16* __restrict__ x2out, bf16* __restrict__ uout)
{
    __shared__ bf16 As[128 * 64];
    __shared__ bf16 Bs[256 * 64];
    const int t = threadIdx.x;
    const int wave = t >> 6, lane = t & 63;
    const int g = lane >> 4, ql = lane & 15;
    const int q8 = gridDim.x >> 3;
    const int o = ((int)blockIdx.x & 7) * q8 + ((int)blockIdx.x >> 3);
    const long m0 = (long)o * 128;
    const int waveM = wave * 16;
    f32x4 acc[16] = {};

    for (int k0 = 0; k0 < 256; k0 += 64) {
        #pragma unroll
        for (int i = 0; i < 2; ++i) {                 // A: 1024 chunks
            int c = i * 512 + t;
            int r = c >> 3, cc = (c & 7) * 8;
            const bf16* ga = A + (m0 + r) * 256 + k0 + cc;
            __builtin_amdgcn_global_load_lds(
                (const AS1 void*)ga, (AS3 void*)(As + c * 8), 16, 0, 0);
        }
        #pragma unroll
        for (int i = 0; i < 4; ++i) {                 // B: 2048 chunks
            int c = i * 512 + t;
            int r = c >> 3, cc = (c & 7) * 8;
            const bf16* gb = Wt + r * 256 + k0 + cc;
            __builtin_amdgcn_global_load_lds(
                (const AS1 void*)gb, (AS3 void*)(Bs + c * 8), 16, 0, 0);
        }
        __syncthreads();
        #pragma unroll
        for (int kk = 0; kk < 2; ++kk) {
            const int krow = kk * 32 + g * 8;
            bf16x8 af = *(const bf16x8*)&As[(waveM + ql) * 64 + krow];
            #pragma unroll
            for (int fn = 0; fn < 16; ++fn) {
                bf16x8 bv = *(const bf16x8*)&Bs[(fn * 16 + ql) * 64 + krow];
                acc[fn] = __builtin_amdgcn_mfma_f32_16x16x32_bf16(af, bv, acc[fn], 0, 0, 0);
            }
        }
        __syncthreads();
    }

    float rsum[4] = {}, rsq[4] = {};
    #pragma unroll
    for (int fn = 0; fn < 16; ++fn) {
        const int n = fn * 16 + ql;
        const float bn = bias[n];
        #pragma unroll
        for (int r = 0; r < 4; ++r) {
            const long m = m0 + waveM + g * 4 + r;
            float v = acc[fn][r] + bn + (float)resid[m * 256 + n];
            acc[fn][r] = v;
            rsum[r] += v; rsq[r] += v * v;
        }
    }
    #pragma unroll
    for (int r = 0; r < 4; ++r) {
        float s = rsum[r], q = rsq[r];
        #pragma unroll
        for (int off = 8; off; off >>= 1) {
            s += __shfl_xor(s, off, 64);
            q += __shfl_xor(q, off, 64);
        }
        float mean = s * (1.0f / 256.0f);
        float var  = q * (1.0f / 256.0f) - mean * mean;
        rsum[r] = mean;
        rsq[r]  = rsqrtf(var + 1e-6f);
    }
    #pragma unroll
    for (int fn = 0; fn < 16; ++fn) {
        const int n = fn * 16 + ql;
        const float gn = g2[n], bn2 = b2[n];
        #pragma unroll
        for (int r = 0; r < 4; ++r) {
            const long m = m0 + waveM + g * 4 + r;
            float v = acc[fn][r];
            x2out[m * 256 + n] = (bf16)v;
            uout[m * 256 + n] = (bf16)((v - rsum[r]) * rsq[r] * gn + bn2);
        }
    }
}

// ------------------------------- launch ----------------------------------
extern "C" void kernel_launch(void* const* d_in, const int* in_sizes, int n_in,
                              void* d_out, int out_size, void* d_ws, size_t ws_size,
                              hipStream_t stream)
{
    (void)in_sizes; (void)n_in; (void)out_size; (void)ws_size;
    const float* x      = (const float*)d_in[0];
    const float* mask_h = (const float*)d_in[1];
    const float* mask_w = (const float*)d_in[2];
    const float* pos_w  = (const float*)d_in[3];
    const float* pos_b  = (const float*)d_in[4];
    const float* ln1_g  = (const float*)d_in[5];
    const float* ln1_b  = (const float*)d_in[6];
    const float* q_w    = (const float*)d_in[7];
    const float* q_b    = (const float*)d_in[8];
    const float* k_w    = (const float*)d_in[9];
    const float* k_b    = (const float*)d_in[10];
    const float* v_w    = (const float*)d_in[11];
    const float* v_b    = (const float*)d_in[12];
    const float* lepe_w = (const float*)d_in[13];
    const float* lepe_b = (const float*)d_in[14];
    const float* out_w  = (const float*)d_in[15];
    const float* out_b  = (const float*)d_in[16];
    const float* ln2_g  = (const float*)d_in[17];
    const float* ln2_b  = (const float*)d_in[18];
    const float* fc1_w  = (const float*)d_in[19];
    const float* fc1_b  = (const float*)d_in[20];
    const float* fc2_w  = (const float*)d_in[21];
    const float* fc2_b  = (const float*)d_in[22];

    char* ws = (char*)d_ws;
    size_t off = 0;
    auto alloc = [&](size_t bytes) -> void* {
        void* p = ws + off;
        off += (bytes + 255) & ~(size_t)255;
        return p;
    };
    const int M = NPIX;
    bf16*  x1     = (bf16*) alloc((size_t)M * 256 * 2);       // x + posconv (bf16 residual)
    bf16*  tln    = (bf16*) alloc((size_t)M * 256 * 2);       // LN1 out
    bf16*  qkv3   = (bf16*) alloc((size_t)M * 768 * 2);       // q|k|v PLANAR (3x M*256)
    bf16*  lepeb  = (bf16*) alloc((size_t)M * 256 * 2);       // lepe; later reused as LN2 out
    bf16*  vwb    = (bf16*) alloc((size_t)M * 256 * 2);       // width-attention output
    bf16*  obuf   = (bf16*) alloc((size_t)M * 256 * 2);       // height-attn out + lepe
    bf16*  x2b    = (bf16*) alloc((size_t)M * 256 * 2);       // x2 trunk (bf16)
    bf16*  wt_qkv = (bf16*) alloc((size_t)768 * 256 * 2);
    bf16*  wt_out = (bf16*) alloc((size_t)256 * 256 * 2);
    bf16*  wt_fc1 = (bf16*) alloc((size_t)1024 * 256 * 2);
    bf16*  wt_fc2 = (bf16*) alloc((size_t)256 * 1024 * 2);
    float* qkvb   = (float*)alloc(768 * 4);
    bf16*  qpl    = qkv3;
    bf16*  kpl    = qkv3 + (size_t)M * 256;
    bf16*  vpl    = qkv3 + (size_t)M * 512;
    bf16*  h1     = tln;   // [M][1024] bf16 = 102.76MB, spans tln+qkv3
    float* outf   = (float*)d_out;

    // 0+1+2. weight prep (+bias) AND posconv+LN1 in one launch
    pre_kernel<<<12544 + 3075, 256, 0, stream>>>(
        x, pos_w, pos_b, ln1_g, ln1_b, x1, tln,
        q_w, k_w, v_w, out_w, fc1_w, fc2_w, q_b, k_b, v_b,
        wt_qkv, wt_out, wt_fc1, wt_fc2, qkvb);

    // 3. q/k/v planes = tln @ [q|k*s|v] + bias  (196 m-tiles x 6 n-tiles)
    gemm_kernel<false, false, true, true><<<196 * 6, 512, 0, stream>>>(
        tln, wt_qkv, qkvb, nullptr, qkv3, M, 768, 256);
    // 4. lepe = dwconv5x5(v), register-blocked vertical-4
    lepe_kernel<<<1568, 256, 0, stream>>>(vpl, lepe_w, lepe_b, lepeb);
    // 5. width-axis attention -> vw
    attn_mfma_kernel<true><<<1792, 256, 0, stream>>>(qpl, kpl, vpl, mask_w, nullptr, vwb);
    // 6. height-axis attention (V = vw) + lepe -> obuf
    attn_mfma_kernel<false><<<1792, 256, 0, stream>>>(qpl, kpl, vwb, mask_h, lepeb, obuf);
    // 7+8. x2 = x1 + obuf @ out_w + out_b -> x2b (bf16);  u = LN2(x2) -> lepeb
    outln_kernel<<<392, 512, 0, stream>>>(
        obuf, wt_out, out_b, x1, ln2_g, ln2_b, x2b, lepeb);
    // 9. h1 = gelu(u @ fc1_w + fc1_b)  (196 x 8 tiles)
    gemm_kernel<true, false, true, false><<<196 * 8, 512, 0, stream>>>(
        lepeb, wt_fc1, fc1_b, nullptr, h1, M, 1024, 256);
    // 10. d_out = x2 + h1 @ fc2_w + fc2_b  (196 x 2 tiles, fp32 out)
    gemm_kernel<false, true, false, false><<<196 * 2, 512, 0, stream>>>(
        h1, wt_fc2, fc2_b, x2b, outf, M, 256, 1024);
}

// Round 17
// 372.181 us; speedup vs baseline: 1.1672x; 1.0217x over previous
//
#include <hip/hip_runtime.h>
#include <hip/hip_bf16.h>
#include <math.h>
#include <stdint.h>

typedef __bf16 bf16;
typedef __bf16 bf16x8 __attribute__((ext_vector_type(8)));
typedef __bf16 bf16x4 __attribute__((ext_vector_type(4)));
typedef float f32x4 __attribute__((ext_vector_type(4)));

#define AS1 __attribute__((address_space(1)))
#define AS3 __attribute__((address_space(3)))

#define NPIX (16*56*56)          // 50176 pixels
#define CH 256
#define SCALE_K 0.17677669529663687f   // 32^-0.5

// gelu(tanh form) == vv * sigmoid(2u); exp2/rcp raw instructions.
__device__ __forceinline__ float gelu_fast(float vv) {
    float t = vv * (-2.30220781f + -0.10294330f * vv * vv);
    float e = __builtin_amdgcn_exp2f(t);
    return vv * __builtin_amdgcn_rcpf(1.0f + e);
}

// ------- fused: [0,12544) posconv+LN1 blocks; [12544,15619) weight prep --
// x1 stored bf16 (residual only; LN1 computed from fp32 regs).
__global__ __launch_bounds__(256) void pre_kernel(
    const float* __restrict__ x, const float* __restrict__ pos_w,
    const float* __restrict__ pos_b, const float* __restrict__ ln1_g,
    const float* __restrict__ ln1_b, bf16* __restrict__ x1,
    bf16* __restrict__ tln,
    const float* __restrict__ q_w, const float* __restrict__ k_w,
    const float* __restrict__ v_w, const float* __restrict__ out_w,
    const float* __restrict__ fc1_w, const float* __restrict__ fc2_w,
    const float* __restrict__ qb, const float* __restrict__ kb,
    const float* __restrict__ vb,
    bf16* __restrict__ wt_qkv, bf16* __restrict__ wt_out,
    bf16* __restrict__ wt_fc1, bf16* __restrict__ wt_fc2,
    float* __restrict__ qkvb)
{
    if (blockIdx.x >= 12544) {
        int idx = (blockIdx.x - 12544) * 256 + threadIdx.x;
        if (idx < 262144) {
            int w = idx >> 16;                 // 0=q 1=k 2=v 3=out
            int j = idx & 65535;
            int n = j >> 8, k = j & 255;
            const float* src = (w == 0) ? q_w : (w == 1) ? k_w : (w == 2) ? v_w : out_w;
            float scale = (w == 1) ? SCALE_K : 1.0f;
            bf16* dst = (w < 3) ? (wt_qkv + w * 65536) : wt_out;
            dst[j] = (bf16)(src[k * 256 + n] * scale);
        } else if (idx < 524288) {
            int j = idx - 262144;
            int n = j >> 8, k = j & 255;
            wt_fc1[j] = (bf16)(fc1_w[k * 1024 + n]);
        } else if (idx < 786432) {
            int j = idx - 524288;
            int n = j >> 10, k = j & 1023;
            wt_fc2[j] = (bf16)(fc2_w[k * 256 + n]);
        } else if (idx < 787200) {
            int i = idx - 786432;
            qkvb[i] = (i < 256) ? qb[i] : (i < 512) ? kb[i - 256] * SCALE_K : vb[i - 512];
        }
        return;
    }
    const int wave = threadIdx.x >> 6, lane = threadIdx.x & 63;
    const long pix = (long)blockIdx.x * 4 + wave;
    const int ww = (int)(pix % 56);
    const int hh = (int)((pix / 56) % 56);
    const int b  = (int)(pix / 3136);
    const int c  = lane * 4;
    float4 acc = ((const float4*)(pos_b + c))[0];
    float4 xin = ((const float4*)(x + pix * 256 + c))[0];
    acc.x += xin.x; acc.y += xin.y; acc.z += xin.z; acc.w += xin.w;
    #pragma unroll
    for (int dh = 0; dh < 3; ++dh) {
        int h2 = hh + dh - 1;
        if (h2 < 0 || h2 >= 56) continue;
        #pragma unroll
        for (int dw = 0; dw < 3; ++dw) {
            int w2 = ww + dw - 1;
            if (w2 < 0 || w2 >= 56) continue;
            float4 xv = ((const float4*)(x + (((long)(b * 56 + h2)) * 56 + w2) * 256 + c))[0];
            float4 wv = ((const float4*)(pos_w + (dh * 3 + dw) * 256 + c))[0];
            acc.x += xv.x * wv.x; acc.y += xv.y * wv.y;
            acc.z += xv.z * wv.z; acc.w += xv.w * wv.w;
        }
    }
    bf16* x1o = x1 + pix * 256 + c;
    x1o[0] = (bf16)acc.x; x1o[1] = (bf16)acc.y;
    x1o[2] = (bf16)acc.z; x1o[3] = (bf16)acc.w;
    float s  = acc.x + acc.y + acc.z + acc.w;
    float q2 = acc.x * acc.x + acc.y * acc.y + acc.z * acc.z + acc.w * acc.w;
    #pragma unroll
    for (int o = 32; o; o >>= 1) {
        s  += __shfl_xor(s,  o, 64);
        q2 += __shfl_xor(q2, o, 64);
    }
    float mean = s * (1.0f / 256.0f);
    float var  = q2 * (1.0f / 256.0f) - mean * mean;
    float rs   = rsqrtf(var + 1e-6f);
    float4 gv = ((const float4*)ln1_g)[lane];
    float4 bv = ((const float4*)ln1_b)[lane];
    bf16* o4 = tln + pix * 256 + c;
    o4[0] = (bf16)((acc.x - mean) * rs * gv.x + bv.x);
    o4[1] = (bf16)((acc.y - mean) * rs * gv.y + bv.y);
    o4[2] = (bf16)((acc.z - mean) * rs * gv.z + bv.z);
    o4[3] = (bf16)((acc.w - mean) * rs * gv.w + bv.w);
}

// ------- 5x5 depthwise conv, register-blocked: 4-pixel column per thread -
// Task order: ww FASTEST (horizontal neighbors temporally adjacent -> L2
// absorbs the 5x horizontal overlap); vertical overlap is in-register.
__global__ __launch_bounds__(256) void lepe_kernel(
    const bf16* __restrict__ vpl, const float* __restrict__ w,
    const float* __restrict__ bias, bf16* __restrict__ out)
{
    long idx = (long)blockIdx.x * 256 + threadIdx.x;   // task*32 + c8
    int c8 = (int)(idx & 31);
    long task = idx >> 5;                              // 12544 tasks
    int ww = (int)(task % 56);
    int hg = (int)((task / 56) % 14);
    int b  = (int)(task / (56 * 14));
    int c  = c8 * 8;
    int h0 = hg * 4;
    float acc[4][8];
    #pragma unroll
    for (int o = 0; o < 4; ++o)
        #pragma unroll
        for (int j = 0; j < 8; ++j) acc[o][j] = bias[c + j];

    #pragma unroll
    for (int rr = 0; rr < 8; ++rr) {
        int h2 = h0 - 2 + rr;
        if (h2 < 0 || h2 >= 56) continue;
        #pragma unroll
        for (int dw = 0; dw < 5; ++dw) {
            int w2 = ww + dw - 2;
            if (w2 < 0 || w2 >= 56) continue;
            bf16x8 vv = *(const bf16x8*)(vpl + (((long)(b * 56 + h2)) * 56 + w2) * 256 + c);
            float f[8];
            #pragma unroll
            for (int j = 0; j < 8; ++j) f[j] = (float)vv[j];
            #pragma unroll
            for (int o = 0; o < 4; ++o) {
                int dh = rr - o;                       // compile-time per (rr,o)
                if (dh < 0 || dh > 4) continue;
                const float4* wp = (const float4*)(w + (dh * 5 + dw) * 256 + c);
                float4 w0 = wp[0], w1 = wp[1];
                acc[o][0] += f[0] * w0.x; acc[o][1] += f[1] * w0.y;
                acc[o][2] += f[2] * w0.z; acc[o][3] += f[3] * w0.w;
                acc[o][4] += f[4] * w1.x; acc[o][5] += f[5] * w1.y;
                acc[o][6] += f[6] * w1.z; acc[o][7] += f[7] * w1.w;
            }
        }
    }
    #pragma unroll
    for (int o = 0; o < 4; ++o) {
        long pix = ((long)(b * 56 + h0 + o)) * 56 + ww;
        bf16* op = out + pix * 256 + c;
        #pragma unroll
        for (int j = 0; j < 8; ++j) op[j] = (bf16)acc[o][j];
    }
}

// ---------------- MFMA attention: one wave per (b, line, head) task ------
template<bool WIDTH>
__global__ __launch_bounds__(256) void attn_mfma_kernel(
    const bf16* __restrict__ qp, const bf16* __restrict__ kp,
    const bf16* __restrict__ vsrc, const float* __restrict__ mask,
    const bf16* __restrict__ lepe, bf16* __restrict__ outp)
{
    __shared__ bf16 VtAll[4][32][72];   // V^T per wave: rows=d(32), cols=pos(64,swz)
    __shared__ bf16 PlAll[4][16][72];   // P per q-tile: rows=q_local(16), cols=kp(64)
    const int tid = threadIdx.x;
    const int wave = tid >> 6, lane = tid & 63;
    const int g = lane >> 4, ql = lane & 15;
    const int n  = blockIdx.x / 224;                  // head
    const int s  = (blockIdx.x % 224) * 4 + wave;     // slab: b*56 + line
    const int b  = s / 56, rc = s % 56;
    bf16 (*Vt)[72] = VtAll[wave];
    bf16 (*Pl)[72] = PlAll[wave];
    const long basePix = WIDTH ? ((long)(b * 56 + rc)) * 56 : (long)b * 3136 + rc;
    const long pixStride = WIDTH ? 1 : 56;
    const long stride = pixStride * 256;
    const bf16* qb = qp + basePix * 256 + n * 32;
    const bf16* kb = kp + basePix * 256 + n * 32;
    const bf16* vbp = vsrc + basePix * 256 + n * 32;

    #pragma unroll
    for (int it = 0; it < 2; ++it) {
        int idx = it * 64 + lane;
        if (idx < 112) {
            int pp = idx >> 2, chunk = idx & 3;
            int pos0 = pp * 2;
            bf16x8 v0 = *(const bf16x8*)(vbp + (long)pos0 * stride + chunk * 8);
            bf16x8 v1 = *(const bf16x8*)(vbp + (long)(pos0 + 1) * stride + chunk * 8);
            int colb = pos0 ^ (chunk << 3);
            #pragma unroll
            for (int j = 0; j < 8; ++j) {
                union { bf16 h[2]; unsigned int u; } pk;
                pk.h[0] = v0[j]; pk.h[1] = v1[j];
                *(unsigned int*)&Vt[chunk * 8 + j][colb] = pk.u;
            }
        }
    }
    if (lane < 32) {
        int d = lane;
        int colb = 56 ^ ((d >> 3) << 3);
        *(float4*)&Vt[d][colb] = (float4){0.f, 0.f, 0.f, 0.f};
    }

    bf16x8 qf[4], kf[4];
    #pragma unroll
    for (int t4 = 0; t4 < 4; ++t4) {
        int row = ql + 16 * t4; if (row > 55) row = 55;
        qf[t4] = *(const bf16x8*)(qb + (long)row * stride + 8 * g);
        kf[t4] = *(const bf16x8*)(kb + (long)row * stride + 8 * g);
    }

    f32x4 sA[4][4];
    __builtin_amdgcn_s_setprio(1);
    #pragma unroll
    for (int qt = 0; qt < 4; ++qt)
        #pragma unroll
        for (int kt = 0; kt < 4; ++kt)
            sA[qt][kt] = __builtin_amdgcn_mfma_f32_16x16x32_bf16(
                kf[kt], qf[qt], (f32x4){0.f, 0.f, 0.f, 0.f}, 0, 0, 0);
    __builtin_amdgcn_s_setprio(0);

    const float* mrow = mask + n * 3136;
    #pragma unroll
    for (int qt = 0; qt < 4; ++qt) {
        int qm = ql + 16 * qt; if (qm > 55) qm = 55;
        #pragma unroll
        for (int kt = 0; kt < 4; ++kt) {
            if (kt == 3 && g >= 2) {
                sA[qt][3][0] = -3.0e38f; sA[qt][3][1] = -3.0e38f;
                sA[qt][3][2] = -3.0e38f; sA[qt][3][3] = -3.0e38f;
            } else {
                float4 mv = *(const float4*)(mrow + qm * 56 + kt * 16 + 4 * g);
                sA[qt][kt][0] += mv.x; sA[qt][kt][1] += mv.y;
                sA[qt][kt][2] += mv.z; sA[qt][kt][3] += mv.w;
            }
        }
    }

    #pragma unroll
    for (int qt = 0; qt < 4; ++qt) {
        float m = -3.0e38f;
        #pragma unroll
        for (int kt = 0; kt < 4; ++kt)
            #pragma unroll
            for (int r = 0; r < 4; ++r) m = fmaxf(m, sA[qt][kt][r]);
        m = fmaxf(m, __shfl_xor(m, 16, 64));
        m = fmaxf(m, __shfl_xor(m, 32, 64));
        float p[4][4];
        float sum = 0.f;
        #pragma unroll
        for (int kt = 0; kt < 4; ++kt)
            #pragma unroll
            for (int r = 0; r < 4; ++r) {
                float e = exp2f((sA[qt][kt][r] - m) * 1.4426950408889634f);
                p[kt][r] = e; sum += e;
            }
        sum += __shfl_xor(sum, 16, 64);
        sum += __shfl_xor(sum, 32, 64);
        float rinv = 1.0f / sum;
        #pragma unroll
        for (int kt = 0; kt < 4; ++kt) {
            bf16x4 w;
            #pragma unroll
            for (int r = 0; r < 4; ++r) w[r] = (bf16)(p[kt][r] * rinv);
            *(bf16x4*)&Pl[ql][kt * 16 + 4 * g] = w;
        }
        #pragma unroll
        for (int nt = 0; nt < 2; ++nt) {
            f32x4 o = {0.f, 0.f, 0.f, 0.f};
            __builtin_amdgcn_s_setprio(1);
            #pragma unroll
            for (int ks = 0; ks < 2; ++ks) {
                bf16x8 af = *(const bf16x8*)&Pl[ql][ks * 32 + 8 * g];
                int vrow = ql + 16 * nt;
                int vcol = (ks * 32 + 8 * g) ^ ((vrow >> 3) << 3);
                bf16x8 bv = *(const bf16x8*)&Vt[vrow][vcol];
                o = __builtin_amdgcn_mfma_f32_16x16x32_bf16(af, bv, o, 0, 0, 0);
            }
            __builtin_amdgcn_s_setprio(0);
            if (!(qt == 3 && g >= 2)) {
                #pragma unroll
                for (int r = 0; r < 4; ++r) {
                    int q = 16 * qt + 4 * g + r;
                    long addr = (basePix + (long)q * pixStride) * 256 + n * 32 + nt * 16 + ql;
                    float vv = o[r];
                    if (!WIDTH) vv += (float)lepe[addr];
                    outp[addr] = (bf16)vv;
                }
            }
        }
    }
}

// ---------------- bf16 MFMA GEMM: 256x128 tile, 8 waves (4M x 2N) --------
// resid is bf16 (fc2's x2 trunk).
template<bool GELU, bool RESID, bool OUT_BF16, bool QKV3>
__global__ __launch_bounds__(512) void gemm_kernel(
    const bf16* __restrict__ A, const bf16* __restrict__ Wt,
    const float* __restrict__ bias, const bf16* __restrict__ resid,
    void* __restrict__ Cout, int M, int N, int K)
{
    __shared__ bf16 As[256 * 64];
    __shared__ bf16 Bs[128 * 64];
    const int t = threadIdx.x;
    const int wave = t >> 6, lane = t & 63;
    const int nTilesN = N >> 7;
    const int q8 = gridDim.x >> 3;                    // T1 swizzle (grid % 8 == 0)
    const int o = ((int)blockIdx.x & 7) * q8 + ((int)blockIdx.x >> 3);
    const int tm = o / nTilesN, tn = o % nTilesN;
    const long m0 = (long)tm * 256, n0 = (long)tn * 128;
    const int waveM = (wave >> 1) * 64, waveN = (wave & 1) * 64;
    f32x4 acc[4][4] = {};

    for (int k0 = 0; k0 < K; k0 += 64) {
        #pragma unroll
        for (int i = 0; i < 4; ++i) {                 // A: 2048 chunks of 16B
            int c = i * 512 + t;
            int r = c >> 3, cc = (c & 7) * 8;
            const bf16* ga = A + (m0 + r) * (long)K + k0 + cc;
            __builtin_amdgcn_global_load_lds(
                (const AS1 void*)ga, (AS3 void*)(As + c * 8), 16, 0, 0);
        }
        #pragma unroll
        for (int i = 0; i < 2; ++i) {                 // B: 1024 chunks of 16B
            int c = i * 512 + t;
            int r = c >> 3, cc = (c & 7) * 8;
            const bf16* gb = Wt + (n0 + r) * (long)K + k0 + cc;
            __builtin_amdgcn_global_load_lds(
                (const AS1 void*)gb, (AS3 void*)(Bs + c * 8), 16, 0, 0);
        }
        __syncthreads();
        #pragma unroll
        for (int kk = 0; kk < 2; ++kk) {
            bf16x8 af[4], bfr[4];
            const int krow = kk * 32 + (lane >> 4) * 8;
            #pragma unroll
            for (int fm = 0; fm < 4; ++fm)
                af[fm] = *(const bf16x8*)&As[(waveM + fm * 16 + (lane & 15)) * 64 + krow];
            #pragma unroll
            for (int fn = 0; fn < 4; ++fn)
                bfr[fn] = *(const bf16x8*)&Bs[(waveN + fn * 16 + (lane & 15)) * 64 + krow];
            #pragma unroll
            for (int fm = 0; fm < 4; ++fm)
                #pragma unroll
                for (int fn = 0; fn < 4; ++fn)
                    acc[fm][fn] = __builtin_amdgcn_mfma_f32_16x16x32_bf16(
                        af[fm], bfr[fn], acc[fm][fn], 0, 0, 0);
        }
        __syncthreads();
    }

    #pragma unroll
    for (int fm = 0; fm < 4; ++fm) {
        #pragma unroll
        for (int r = 0; r < 4; ++r) {
            const long m = m0 + waveM + fm * 16 + (lane >> 4) * 4 + r;
            #pragma unroll
            for (int fn = 0; fn < 4; ++fn) {
                const long n = n0 + waveN + fn * 16 + (lane & 15);
                float vv = acc[fm][fn][r] + bias[n];
                if (GELU)  vv = gelu_fast(vv);
                if (RESID) vv += (float)resid[m * N + n];
                if (QKV3) {
                    long pl = n >> 8;
                    ((bf16*)Cout)[pl * (long)NPIX * 256 + m * 256 + (n & 255)] = (bf16)vv;
                } else if (OUT_BF16) {
                    ((bf16*)Cout)[m * N + n] = (bf16)vv;
                } else {
                    ((float*)Cout)[m * N + n] = vv;
                }
            }
        }
    }
}

// ------- fused out-proj GEMM + residual(bf16) + LayerNorm2 --------------
// x2 trunk stored bf16 (LN2 computed from fp32 regs; fc2 re-reads bf16).
__global__ __launch_bounds__(512) void outln_kernel(
    const bf16* __restrict__ A, const bf16* __restrict__ Wt,
    const float* __restrict__ bias, const bf16* __restrict__ resid,
    const float* __restrict__ g2, const float* __restrict__ b2,
    bf16* __restrict__ x2out, bf16* __restrict__ uout)
{
    __shared__ bf16 As[128 * 64];
    __shared__ bf16 Bs[256 * 64];
    const int t = threadIdx.x;
    const int wave = t >> 6, lane = t & 63;
    const int g = lane >> 4, ql = lane & 15;
    const int q8 = gridDim.x >> 3;
    const int o = ((int)blockIdx.x & 7) * q8 + ((int)blockIdx.x >> 3);
    const long m0 = (long)o * 128;
    const int waveM = wave * 16;
    f32x4 acc[16] = {};

    for (int k0 = 0; k0 < 256; k0 += 64) {
        #pragma unroll
        for (int i = 0; i < 2; ++i) {                 // A: 1024 chunks
            int c = i * 512 + t;
            int r = c >> 3, cc = (c & 7) * 8;
            const bf16* ga = A + (m0 + r) * 256 + k0 + cc;
            __builtin_amdgcn_global_load_lds(
                (const AS1 void*)ga, (AS3 void*)(As + c * 8), 16, 0, 0);
        }
        #pragma unroll
        for (int i = 0; i < 4; ++i) {                 // B: 2048 chunks
            int c = i * 512 + t;
            int r = c >> 3, cc = (c & 7) * 8;
            const bf16* gb = Wt + r * 256 + k0 + cc;
            __builtin_amdgcn_global_load_lds(
                (const AS1 void*)gb, (AS3 void*)(Bs + c * 8), 16, 0, 0);
        }
        __syncthreads();
        #pragma unroll
        for (int kk = 0; kk < 2; ++kk) {
            const int krow = kk * 32 + g * 8;
            bf16x8 af = *(const bf16x8*)&As[(waveM + ql) * 64 + krow];
            #pragma unroll
            for (int fn = 0; fn < 16; ++fn) {
                bf16x8 bv = *(const bf16x8*)&Bs[(fn * 16 + ql) * 64 + krow];
                acc[fn] = __builtin_amdgcn_mfma_f32_16x16x32_bf16(af, bv, acc[fn], 0, 0, 0);
            }
        }
        __syncthreads();
    }

    float rsum[4] = {}, rsq[4] = {};
    #pragma unroll
    for (int fn = 0; fn < 16; ++fn) {
        const int n = fn * 16 + ql;
        const float bn = bias[n];
        #pragma unroll
        for (int r = 0; r < 4; ++r) {
            const long m = m0 + waveM + g * 4 + r;
            float v = acc[fn][r] + bn + (float)resid[m * 256 + n];
            acc[fn][r] = v;
            rsum[r] += v; rsq[r] += v * v;
        }
    }
    #pragma unroll
    for (int r = 0; r < 4; ++r) {
        float s = rsum[r], q = rsq[r];
        #pragma unroll
        for (int off = 8; off; off >>= 1) {
            s += __shfl_xor(s, off, 64);
            q += __shfl_xor(q, off, 64);
        }
        float mean = s * (1.0f / 256.0f);
        float var  = q * (1.0f / 256.0f) - mean * mean;
        rsum[r] = mean;
        rsq[r]  = rsqrtf(var + 1e-6f);
    }
    #pragma unroll
    for (int fn = 0; fn < 16; ++fn) {
        const int n = fn * 16 + ql;
        const float gn = g2[n], bn2 = b2[n];
        #pragma unroll
        for (int r = 0; r < 4; ++r) {
            const long m = m0 + waveM + g * 4 + r;
            float v = acc[fn][r];
            x2out[m * 256 + n] = (bf16)v;
            uout[m * 256 + n] = (bf16)((v - rsum[r]) * rsq[r] * gn + bn2);
        }
    }
}

// ------------------------------- launch ----------------------------------
extern "C" void kernel_launch(void* const* d_in, const int* in_sizes, int n_in,
                              void* d_out, int out_size, void* d_ws, size_t ws_size,
                              hipStream_t stream)
{
    (void)in_sizes; (void)n_in; (void)out_size; (void)ws_size;
    const float* x      = (const float*)d_in[0];
    const float* mask_h = (const float*)d_in[1];
    const float* mask_w = (const float*)d_in[2];
    const float* pos_w  = (const float*)d_in[3];
    const float* pos_b  = (const float*)d_in[4];
    const float* ln1_g  = (const float*)d_in[5];
    const float* ln1_b  = (const float*)d_in[6];
    const float* q_w    = (const float*)d_in[7];
    const float* q_b    = (const float*)d_in[8];
    const float* k_w    = (const float*)d_in[9];
    const float* k_b    = (const float*)d_in[10];
    const float* v_w    = (const float*)d_in[11];
    const float* v_b    = (const float*)d_in[12];
    const float* lepe_w = (const float*)d_in[13];
    const float* lepe_b = (const float*)d_in[14];
    const float* out_w  = (const float*)d_in[15];
    const float* out_b  = (const float*)d_in[16];
    const float* ln2_g  = (const float*)d_in[17];
    const float* ln2_b  = (const float*)d_in[18];
    const float* fc1_w  = (const float*)d_in[19];
    const float* fc1_b  = (const float*)d_in[20];
    const float* fc2_w  = (const float*)d_in[21];
    const float* fc2_b  = (const float*)d_in[22];

    char* ws = (char*)d_ws;
    size_t off = 0;
    auto alloc = [&](size_t bytes) -> void* {
        void* p = ws + off;
        off += (bytes + 255) & ~(size_t)255;
        return p;
    };
    const int M = NPIX;
    bf16*  x1     = (bf16*) alloc((size_t)M * 256 * 2);       // x + posconv (bf16 residual)
    bf16*  tln    = (bf16*) alloc((size_t)M * 256 * 2);       // LN1 out
    bf16*  qkv3   = (bf16*) alloc((size_t)M * 768 * 2);       // q|k|v PLANAR (3x M*256)
    bf16*  lepeb  = (bf16*) alloc((size_t)M * 256 * 2);       // lepe; later reused as LN2 out
    bf16*  vwb    = (bf16*) alloc((size_t)M * 256 * 2);       // width-attention output
    bf16*  obuf   = (bf16*) alloc((size_t)M * 256 * 2);       // height-attn out + lepe
    bf16*  x2b    = (bf16*) alloc((size_t)M * 256 * 2);       // x2 trunk (bf16)
    bf16*  wt_qkv = (bf16*) alloc((size_t)768 * 256 * 2);
    bf16*  wt_out = (bf16*) alloc((size_t)256 * 256 * 2);
    bf16*  wt_fc1 = (bf16*) alloc((size_t)1024 * 256 * 2);
    bf16*  wt_fc2 = (bf16*) alloc((size_t)256 * 1024 * 2);
    float* qkvb   = (float*)alloc(768 * 4);
    bf16*  qpl    = qkv3;
    bf16*  kpl    = qkv3 + (size_t)M * 256;
    bf16*  vpl    = qkv3 + (size_t)M * 512;
    bf16*  h1     = tln;   // [M][1024] bf16 = 102.76MB, spans tln+qkv3
    float* outf   = (float*)d_out;

    // 0+1+2. weight prep (+bias) AND posconv+LN1 in one launch
    pre_kernel<<<12544 + 3075, 256, 0, stream>>>(
        x, pos_w, pos_b, ln1_g, ln1_b, x1, tln,
        q_w, k_w, v_w, out_w, fc1_w, fc2_w, q_b, k_b, v_b,
        wt_qkv, wt_out, wt_fc1, wt_fc2, qkvb);

    // 3. q/k/v planes = tln @ [q|k*s|v] + bias  (196 m-tiles x 6 n-tiles)
    gemm_kernel<false, false, true, true><<<196 * 6, 512, 0, stream>>>(
        tln, wt_qkv, qkvb, nullptr, qkv3, M, 768, 256);
    // 4. lepe = dwconv5x5(v), register-blocked vertical-4, ww-fastest order
    lepe_kernel<<<1568, 256, 0, stream>>>(vpl, lepe_w, lepe_b, lepeb);
    // 5. width-axis attention -> vw
    attn_mfma_kernel<true><<<1792, 256, 0, stream>>>(qpl, kpl, vpl, mask_w, nullptr, vwb);
    // 6. height-axis attention (V = vw) + lepe -> obuf
    attn_mfma_kernel<false><<<1792, 256, 0, stream>>>(qpl, kpl, vwb, mask_h, lepeb, obuf);
    // 7+8. x2 = x1 + obuf @ out_w + out_b -> x2b (bf16);  u = LN2(x2) -> lepeb
    outln_kernel<<<392, 512, 0, stream>>>(
        obuf, wt_out, out_b, x1, ln2_g, ln2_b, x2b, lepeb);
    // 9. h1 = gelu(u @ fc1_w + fc1_b)  (196 x 8 tiles)
    gemm_kernel<true, false, true, false><<<196 * 8, 512, 0, stream>>>(
        lepeb, wt_fc1, fc1_b, nullptr, h1, M, 1024, 256);
    // 10. d_out = x2 + h1 @ fc2_w + fc2_b  (196 x 2 tiles, fp32 out)
    gemm_kernel<false, true, false, false><<<196 * 2, 512, 0, stream>>>(
        h1, wt_fc2, fc2_b, x2b, outf, M, 256, 1024);
}

// Round 18
// 361.015 us; speedup vs baseline: 1.2033x; 1.0309x over previous
//
#include <hip/hip_runtime.h>
#include <hip/hip_bf16.h>
#include <math.h>
#include <stdint.h>

typedef __bf16 bf16;
typedef __bf16 bf16x8 __attribute__((ext_vector_type(8)));
typedef __bf16 bf16x4 __attribute__((ext_vector_type(4)));
typedef float f32x4 __attribute__((ext_vector_type(4)));

#define AS1 __attribute__((address_space(1)))
#define AS3 __attribute__((address_space(3)))

#define NPIX (16*56*56)          // 50176 pixels
#define CH 256
#define SCALE_K 0.17677669529663687f   // 32^-0.5

// gelu(tanh form) == vv * sigmoid(2u); exp2/rcp raw instructions.
__device__ __forceinline__ float gelu_fast(float vv) {
    float t = vv * (-2.30220781f + -0.10294330f * vv * vv);
    float e = __builtin_amdgcn_exp2f(t);
    return vv * __builtin_amdgcn_rcpf(1.0f + e);
}

// ------- fused: [0,6272) posconv+LN1 pixel-PAIR blocks; then weight prep -
// One wave per vertical pixel pair (h0, h0+1): 12 tap loads + 9 weight
// loads per pair (vs 19/pixel); both LN reductions share the wave.
// x1 stored bf16 (residual only; LN1 computed from fp32 regs).
__global__ __launch_bounds__(256) void pre_kernel(
    const float* __restrict__ x, const float* __restrict__ pos_w,
    const float* __restrict__ pos_b, const float* __restrict__ ln1_g,
    const float* __restrict__ ln1_b, bf16* __restrict__ x1,
    bf16* __restrict__ tln,
    const float* __restrict__ q_w, const float* __restrict__ k_w,
    const float* __restrict__ v_w, const float* __restrict__ out_w,
    const float* __restrict__ fc1_w, const float* __restrict__ fc2_w,
    const float* __restrict__ qb, const float* __restrict__ kb,
    const float* __restrict__ vb,
    bf16* __restrict__ wt_qkv, bf16* __restrict__ wt_out,
    bf16* __restrict__ wt_fc1, bf16* __restrict__ wt_fc2,
    float* __restrict__ qkvb)
{
    if (blockIdx.x >= 6272) {
        int idx = (blockIdx.x - 6272) * 256 + threadIdx.x;
        if (idx < 262144) {
            int w = idx >> 16;                 // 0=q 1=k 2=v 3=out
            int j = idx & 65535;
            int n = j >> 8, k = j & 255;
            const float* src = (w == 0) ? q_w : (w == 1) ? k_w : (w == 2) ? v_w : out_w;
            float scale = (w == 1) ? SCALE_K : 1.0f;
            bf16* dst = (w < 3) ? (wt_qkv + w * 65536) : wt_out;
            dst[j] = (bf16)(src[k * 256 + n] * scale);
        } else if (idx < 524288) {
            int j = idx - 262144;
            int n = j >> 8, k = j & 255;
            wt_fc1[j] = (bf16)(fc1_w[k * 1024 + n]);
        } else if (idx < 786432) {
            int j = idx - 524288;
            int n = j >> 10, k = j & 1023;
            wt_fc2[j] = (bf16)(fc2_w[k * 256 + n]);
        } else if (idx < 787200) {
            int i = idx - 786432;
            qkvb[i] = (i < 256) ? qb[i] : (i < 512) ? kb[i - 256] * SCALE_K : vb[i - 512];
        }
        return;
    }
    const int wave = threadIdx.x >> 6, lane = threadIdx.x & 63;
    const long pid = (long)blockIdx.x * 4 + wave;       // pixel-pair id (25088)
    const int ww = (int)(pid % 56);
    const int hp = (int)((pid / 56) % 28);
    const int b  = (int)(pid / (56 * 28));
    const int h0 = hp * 2;
    const int c  = lane * 4;

    float4 row[4][3];
    #pragma unroll
    for (int rr = 0; rr < 4; ++rr) {
        int h2 = h0 - 1 + rr;
        bool vh = (h2 >= 0) && (h2 < 56);
        #pragma unroll
        for (int dc = 0; dc < 3; ++dc) {
            int w2 = ww - 1 + dc;
            bool ok = vh && (w2 >= 0) && (w2 < 56);
            row[rr][dc] = ok
                ? ((const float4*)(x + (((long)(b * 56 + h2)) * 56 + w2) * 256 + c))[0]
                : (float4){0.f, 0.f, 0.f, 0.f};
        }
    }
    float4 wv[3][3];
    #pragma unroll
    for (int dh = 0; dh < 3; ++dh)
        #pragma unroll
        for (int dc = 0; dc < 3; ++dc)
            wv[dh][dc] = ((const float4*)(pos_w + (dh * 3 + dc) * 256 + c))[0];

    float4 bb = ((const float4*)(pos_b + c))[0];
    float4 a0, a1;
    a0.x = bb.x + row[1][1].x; a0.y = bb.y + row[1][1].y;
    a0.z = bb.z + row[1][1].z; a0.w = bb.w + row[1][1].w;
    a1.x = bb.x + row[2][1].x; a1.y = bb.y + row[2][1].y;
    a1.z = bb.z + row[2][1].z; a1.w = bb.w + row[2][1].w;
    #pragma unroll
    for (int dh = 0; dh < 3; ++dh)
        #pragma unroll
        for (int dc = 0; dc < 3; ++dc) {
            float4 w4 = wv[dh][dc];
            float4 r0 = row[dh][dc];
            float4 r1 = row[dh + 1][dc];
            a0.x += r0.x * w4.x; a0.y += r0.y * w4.y;
            a0.z += r0.z * w4.z; a0.w += r0.w * w4.w;
            a1.x += r1.x * w4.x; a1.y += r1.y * w4.y;
            a1.z += r1.z * w4.z; a1.w += r1.w * w4.w;
        }

    const long pix0 = ((long)(b * 56 + h0)) * 56 + ww;
    const long pix1 = pix0 + 56;
    bf16* x1o0 = x1 + pix0 * 256 + c;
    bf16* x1o1 = x1 + pix1 * 256 + c;
    x1o0[0] = (bf16)a0.x; x1o0[1] = (bf16)a0.y; x1o0[2] = (bf16)a0.z; x1o0[3] = (bf16)a0.w;
    x1o1[0] = (bf16)a1.x; x1o1[1] = (bf16)a1.y; x1o1[2] = (bf16)a1.z; x1o1[3] = (bf16)a1.w;

    float s0 = a0.x + a0.y + a0.z + a0.w;
    float q0 = a0.x * a0.x + a0.y * a0.y + a0.z * a0.z + a0.w * a0.w;
    float s1 = a1.x + a1.y + a1.z + a1.w;
    float q1 = a1.x * a1.x + a1.y * a1.y + a1.z * a1.z + a1.w * a1.w;
    #pragma unroll
    for (int o = 32; o; o >>= 1) {
        s0 += __shfl_xor(s0, o, 64);
        q0 += __shfl_xor(q0, o, 64);
        s1 += __shfl_xor(s1, o, 64);
        q1 += __shfl_xor(q1, o, 64);
    }
    float m0 = s0 * (1.0f / 256.0f);
    float v0 = q0 * (1.0f / 256.0f) - m0 * m0;
    float r0 = rsqrtf(v0 + 1e-6f);
    float m1 = s1 * (1.0f / 256.0f);
    float v1 = q1 * (1.0f / 256.0f) - m1 * m1;
    float r1 = rsqrtf(v1 + 1e-6f);
    float4 gv = ((const float4*)ln1_g)[lane];
    float4 bv = ((const float4*)ln1_b)[lane];
    bf16* o0 = tln + pix0 * 256 + c;
    bf16* o1 = tln + pix1 * 256 + c;
    o0[0] = (bf16)((a0.x - m0) * r0 * gv.x + bv.x);
    o0[1] = (bf16)((a0.y - m0) * r0 * gv.y + bv.y);
    o0[2] = (bf16)((a0.z - m0) * r0 * gv.z + bv.z);
    o0[3] = (bf16)((a0.w - m0) * r0 * gv.w + bv.w);
    o1[0] = (bf16)((a1.x - m1) * r1 * gv.x + bv.x);
    o1[1] = (bf16)((a1.y - m1) * r1 * gv.y + bv.y);
    o1[2] = (bf16)((a1.z - m1) * r1 * gv.z + bv.z);
    o1[3] = (bf16)((a1.w - m1) * r1 * gv.w + bv.w);
}

// ------- 5x5 depthwise conv, register-blocked: 4-pixel column per thread -
__global__ __launch_bounds__(256) void lepe_kernel(
    const bf16* __restrict__ vpl, const float* __restrict__ w,
    const float* __restrict__ bias, bf16* __restrict__ out)
{
    long idx = (long)blockIdx.x * 256 + threadIdx.x;   // task*32 + c8
    int c8 = (int)(idx & 31);
    long task = idx >> 5;                              // 12544 tasks
    int ww = (int)(task % 56);
    int hg = (int)((task / 56) % 14);
    int b  = (int)(task / (56 * 14));
    int c  = c8 * 8;
    int h0 = hg * 4;
    float acc[4][8];
    #pragma unroll
    for (int o = 0; o < 4; ++o)
        #pragma unroll
        for (int j = 0; j < 8; ++j) acc[o][j] = bias[c + j];

    #pragma unroll
    for (int rr = 0; rr < 8; ++rr) {
        int h2 = h0 - 2 + rr;
        if (h2 < 0 || h2 >= 56) continue;
        #pragma unroll
        for (int dw = 0; dw < 5; ++dw) {
            int w2 = ww + dw - 2;
            if (w2 < 0 || w2 >= 56) continue;
            bf16x8 vv = *(const bf16x8*)(vpl + (((long)(b * 56 + h2)) * 56 + w2) * 256 + c);
            float f[8];
            #pragma unroll
            for (int j = 0; j < 8; ++j) f[j] = (float)vv[j];
            #pragma unroll
            for (int o = 0; o < 4; ++o) {
                int dh = rr - o;                       // compile-time per (rr,o)
                if (dh < 0 || dh > 4) continue;
                const float4* wp = (const float4*)(w + (dh * 5 + dw) * 256 + c);
                float4 w0 = wp[0], w1 = wp[1];
                acc[o][0] += f[0] * w0.x; acc[o][1] += f[1] * w0.y;
                acc[o][2] += f[2] * w0.z; acc[o][3] += f[3] * w0.w;
                acc[o][4] += f[4] * w1.x; acc[o][5] += f[5] * w1.y;
                acc[o][6] += f[6] * w1.z; acc[o][7] += f[7] * w1.w;
            }
        }
    }
    #pragma unroll
    for (int o = 0; o < 4; ++o) {
        long pix = ((long)(b * 56 + h0 + o)) * 56 + ww;
        bf16* op = out + pix * 256 + c;
        #pragma unroll
        for (int j = 0; j < 8; ++j) op[j] = (bf16)acc[o][j];
    }
}

// ---------------- MFMA attention: one wave per (b, line, head) task ------
template<bool WIDTH>
__global__ __launch_bounds__(256) void attn_mfma_kernel(
    const bf16* __restrict__ qp, const bf16* __restrict__ kp,
    const bf16* __restrict__ vsrc, const float* __restrict__ mask,
    const bf16* __restrict__ lepe, bf16* __restrict__ outp)
{
    __shared__ bf16 VtAll[4][32][72];   // V^T per wave: rows=d(32), cols=pos(64,swz)
    __shared__ bf16 PlAll[4][16][72];   // P per q-tile: rows=q_local(16), cols=kp(64)
    const int tid = threadIdx.x;
    const int wave = tid >> 6, lane = tid & 63;
    const int g = lane >> 4, ql = lane & 15;
    const int n  = blockIdx.x / 224;                  // head
    const int s  = (blockIdx.x % 224) * 4 + wave;     // slab: b*56 + line
    const int b  = s / 56, rc = s % 56;
    bf16 (*Vt)[72] = VtAll[wave];
    bf16 (*Pl)[72] = PlAll[wave];
    const long basePix = WIDTH ? ((long)(b * 56 + rc)) * 56 : (long)b * 3136 + rc;
    const long pixStride = WIDTH ? 1 : 56;
    const long stride = pixStride * 256;
    const bf16* qb = qp + basePix * 256 + n * 32;
    const bf16* kb = kp + basePix * 256 + n * 32;
    const bf16* vbp = vsrc + basePix * 256 + n * 32;

    #pragma unroll
    for (int it = 0; it < 2; ++it) {
        int idx = it * 64 + lane;
        if (idx < 112) {
            int pp = idx >> 2, chunk = idx & 3;
            int pos0 = pp * 2;
            bf16x8 v0 = *(const bf16x8*)(vbp + (long)pos0 * stride + chunk * 8);
            bf16x8 v1 = *(const bf16x8*)(vbp + (long)(pos0 + 1) * stride + chunk * 8);
            int colb = pos0 ^ (chunk << 3);
            #pragma unroll
            for (int j = 0; j < 8; ++j) {
                union { bf16 h[2]; unsigned int u; } pk;
                pk.h[0] = v0[j]; pk.h[1] = v1[j];
                *(unsigned int*)&Vt[chunk * 8 + j][colb] = pk.u;
            }
        }
    }
    if (lane < 32) {
        int d = lane;
        int colb = 56 ^ ((d >> 3) << 3);
        *(float4*)&Vt[d][colb] = (float4){0.f, 0.f, 0.f, 0.f};
    }

    bf16x8 qf[4], kf[4];
    #pragma unroll
    for (int t4 = 0; t4 < 4; ++t4) {
        int row = ql + 16 * t4; if (row > 55) row = 55;
        qf[t4] = *(const bf16x8*)(qb + (long)row * stride + 8 * g);
        kf[t4] = *(const bf16x8*)(kb + (long)row * stride + 8 * g);
    }

    f32x4 sA[4][4];
    __builtin_amdgcn_s_setprio(1);
    #pragma unroll
    for (int qt = 0; qt < 4; ++qt)
        #pragma unroll
        for (int kt = 0; kt < 4; ++kt)
            sA[qt][kt] = __builtin_amdgcn_mfma_f32_16x16x32_bf16(
                kf[kt], qf[qt], (f32x4){0.f, 0.f, 0.f, 0.f}, 0, 0, 0);
    __builtin_amdgcn_s_setprio(0);

    const float* mrow = mask + n * 3136;
    #pragma unroll
    for (int qt = 0; qt < 4; ++qt) {
        int qm = ql + 16 * qt; if (qm > 55) qm = 55;
        #pragma unroll
        for (int kt = 0; kt < 4; ++kt) {
            if (kt == 3 && g >= 2) {
                sA[qt][3][0] = -3.0e38f; sA[qt][3][1] = -3.0e38f;
                sA[qt][3][2] = -3.0e38f; sA[qt][3][3] = -3.0e38f;
            } else {
                float4 mv = *(const float4*)(mrow + qm * 56 + kt * 16 + 4 * g);
                sA[qt][kt][0] += mv.x; sA[qt][kt][1] += mv.y;
                sA[qt][kt][2] += mv.z; sA[qt][kt][3] += mv.w;
            }
        }
    }

    #pragma unroll
    for (int qt = 0; qt < 4; ++qt) {
        float m = -3.0e38f;
        #pragma unroll
        for (int kt = 0; kt < 4; ++kt)
            #pragma unroll
            for (int r = 0; r < 4; ++r) m = fmaxf(m, sA[qt][kt][r]);
        m = fmaxf(m, __shfl_xor(m, 16, 64));
        m = fmaxf(m, __shfl_xor(m, 32, 64));
        float p[4][4];
        float sum = 0.f;
        #pragma unroll
        for (int kt = 0; kt < 4; ++kt)
            #pragma unroll
            for (int r = 0; r < 4; ++r) {
                float e = exp2f((sA[qt][kt][r] - m) * 1.4426950408889634f);
                p[kt][r] = e; sum += e;
            }
        sum += __shfl_xor(sum, 16, 64);
        sum += __shfl_xor(sum, 32, 64);
        float rinv = 1.0f / sum;
        #pragma unroll
        for (int kt = 0; kt < 4; ++kt) {
            bf16x4 w;
            #pragma unroll
            for (int r = 0; r < 4; ++r) w[r] = (bf16)(p[kt][r] * rinv);
            *(bf16x4*)&Pl[ql][kt * 16 + 4 * g] = w;
        }
        #pragma unroll
        for (int nt = 0; nt < 2; ++nt) {
            f32x4 o = {0.f, 0.f, 0.f, 0.f};
            __builtin_amdgcn_s_setprio(1);
            #pragma unroll
            for (int ks = 0; ks < 2; ++ks) {
                bf16x8 af = *(const bf16x8*)&Pl[ql][ks * 32 + 8 * g];
                int vrow = ql + 16 * nt;
                int vcol = (ks * 32 + 8 * g) ^ ((vrow >> 3) << 3);
                bf16x8 bv = *(const bf16x8*)&Vt[vrow][vcol];
                o = __builtin_amdgcn_mfma_f32_16x16x32_bf16(af, bv, o, 0, 0, 0);
            }
            __builtin_amdgcn_s_setprio(0);
            if (!(qt == 3 && g >= 2)) {
                #pragma unroll
                for (int r = 0; r < 4; ++r) {
                    int q = 16 * qt + 4 * g + r;
                    long addr = (basePix + (long)q * pixStride) * 256 + n * 32 + nt * 16 + ql;
                    float vv = o[r];
                    if (!WIDTH) vv += (float)lepe[addr];
                    outp[addr] = (bf16)vv;
                }
            }
        }
    }
}

// ---------------- bf16 MFMA GEMM: 256x128 tile, 8 waves (4M x 2N) --------
// resid is bf16 (fc2's x2 trunk).
template<bool GELU, bool RESID, bool OUT_BF16, bool QKV3>
__global__ __launch_bounds__(512) void gemm_kernel(
    const bf16* __restrict__ A, const bf16* __restrict__ Wt,
    const float* __restrict__ bias, const bf16* __restrict__ resid,
    void* __restrict__ Cout, int M, int N, int K)
{
    __shared__ bf16 As[256 * 64];
    __shared__ bf16 Bs[128 * 64];
    const int t = threadIdx.x;
    const int wave = t >> 6, lane = t & 63;
    const int nTilesN = N >> 7;
    const int q8 = gridDim.x >> 3;                    // T1 swizzle (grid % 8 == 0)
    const int o = ((int)blockIdx.x & 7) * q8 + ((int)blockIdx.x >> 3);
    const int tm = o / nTilesN, tn = o % nTilesN;
    const long m0 = (long)tm * 256, n0 = (long)tn * 128;
    const int waveM = (wave >> 1) * 64, waveN = (wave & 1) * 64;
    f32x4 acc[4][4] = {};

    for (int k0 = 0; k0 < K; k0 += 64) {
        #pragma unroll
        for (int i = 0; i < 4; ++i) {                 // A: 2048 chunks of 16B
            int c = i * 512 + t;
            int r = c >> 3, cc = (c & 7) * 8;
            const bf16* ga = A + (m0 + r) * (long)K + k0 + cc;
            __builtin_amdgcn_global_load_lds(
                (const AS1 void*)ga, (AS3 void*)(As + c * 8), 16, 0, 0);
        }
        #pragma unroll
        for (int i = 0; i < 2; ++i) {                 // B: 1024 chunks of 16B
            int c = i * 512 + t;
            int r = c >> 3, cc = (c & 7) * 8;
            const bf16* gb = Wt + (n0 + r) * (long)K + k0 + cc;
            __builtin_amdgcn_global_load_lds(
                (const AS1 void*)gb, (AS3 void*)(Bs + c * 8), 16, 0, 0);
        }
        __syncthreads();
        #pragma unroll
        for (int kk = 0; kk < 2; ++kk) {
            bf16x8 af[4], bfr[4];
            const int krow = kk * 32 + (lane >> 4) * 8;
            #pragma unroll
            for (int fm = 0; fm < 4; ++fm)
                af[fm] = *(const bf16x8*)&As[(waveM + fm * 16 + (lane & 15)) * 64 + krow];
            #pragma unroll
            for (int fn = 0; fn < 4; ++fn)
                bfr[fn] = *(const bf16x8*)&Bs[(waveN + fn * 16 + (lane & 15)) * 64 + krow];
            #pragma unroll
            for (int fm = 0; fm < 4; ++fm)
                #pragma unroll
                for (int fn = 0; fn < 4; ++fn)
                    acc[fm][fn] = __builtin_amdgcn_mfma_f32_16x16x32_bf16(
                        af[fm], bfr[fn], acc[fm][fn], 0, 0, 0);
        }
        __syncthreads();
    }

    #pragma unroll
    for (int fm = 0; fm < 4; ++fm) {
        #pragma unroll
        for (int r = 0; r < 4; ++r) {
            const long m = m0 + waveM + fm * 16 + (lane >> 4) * 4 + r;
            #pragma unroll
            for (int fn = 0; fn < 4; ++fn) {
                const long n = n0 + waveN + fn * 16 + (lane & 15);
                float vv = acc[fm][fn][r] + bias[n];
                if (GELU)  vv = gelu_fast(vv);
                if (RESID) vv += (float)resid[m * N + n];
                if (QKV3) {
                    long pl = n >> 8;
                    ((bf16*)Cout)[pl * (long)NPIX * 256 + m * 256 + (n & 255)] = (bf16)vv;
                } else if (OUT_BF16) {
                    ((bf16*)Cout)[m * N + n] = (bf16)vv;
                } else {
                    ((float*)Cout)[m * N + n] = vv;
                }
            }
        }
    }
}

// ------- fused out-proj GEMM + residual(bf16) + LayerNorm2 --------------
__global__ __launch_bounds__(512) void outln_kernel(
    const bf16* __restrict__ A, const bf16* __restrict__ Wt,
    const float* __restrict__ bias, const bf16* __restrict__ resid,
    const float* __restrict__ g2, const float* __restrict__ b2,
    bf16* __restrict__ x2out, bf16* __restrict__ uout)
{
    __shared__ bf16 As[128 * 64];
    __shared__ bf16 Bs[256 * 64];
    const int t = threadIdx.x;
    const int wave = t >> 6, lane = t & 63;
    const int g = lane >> 4, ql = lane & 15;
    const int q8 = gridDim.x >> 3;
    const int o = ((int)blockIdx.x & 7) * q8 + ((int)blockIdx.x >> 3);
    const long m0 = (long)o * 128;
    const int waveM = wave * 16;
    f32x4 acc[16] = {};

    for (int k0 = 0; k0 < 256; k0 += 64) {
        #pragma unroll
        for (int i = 0; i < 2; ++i) {                 // A: 1024 chunks
            int c = i * 512 + t;
            int r = c >> 3, cc = (c & 7) * 8;
            const bf16* ga = A + (m0 + r) * 256 + k0 + cc;
            __builtin_amdgcn_global_load_lds(
                (const AS1 void*)ga, (AS3 void*)(As + c * 8), 16, 0, 0);
        }
        #pragma unroll
        for (int i = 0; i < 4; ++i) {                 // B: 2048 chunks
            int c = i * 512 + t;
            int r = c >> 3, cc = (c & 7) * 8;
            const bf16* gb = Wt + r * 256 + k0 + cc;
            __builtin_amdgcn_global_load_lds(
                (const AS1 void*)gb, (AS3 void*)(Bs + c * 8), 16, 0, 0);
        }
        __syncthreads();
        #pragma unroll
        for (int kk = 0; kk < 2; ++kk) {
            const int krow = kk * 32 + g * 8;
            bf16x8 af = *(const bf16x8*)&As[(waveM + ql) * 64 + krow];
            #pragma unroll
            for (int fn = 0; fn < 16; ++fn) {
                bf16x8 bv = *(const bf16x8*)&Bs[(fn * 16 + ql) * 64 + krow];
                acc[fn] = __builtin_amdgcn_mfma_f32_16x16x32_bf16(af, bv, acc[fn], 0, 0, 0);
            }
        }
        __syncthreads();
    }

    float rsum[4] = {}, rsq[4] = {};
    #pragma unroll
    for (int fn = 0; fn < 16; ++fn) {
        const int n = fn * 16 + ql;
        const float bn = bias[n];
        #pragma unroll
        for (int r = 0; r < 4; ++r) {
            const long m = m0 + waveM + g * 4 + r;
            float v = acc[fn][r] + bn + (float)resid[m * 256 + n];
            acc[fn][r] = v;
            rsum[r] += v; rsq[r] += v * v;
        }
    }
    #pragma unroll
    for (int r = 0; r < 4; ++r) {
        float s = rsum[r], q = rsq[r];
        #pragma unroll
        for (int off = 8; off; off >>= 1) {
            s += __shfl_xor(s, off, 64);
            q += __shfl_xor(q, off, 64);
        }
        float mean = s * (1.0f / 256.0f);
        float var  = q * (1.0f / 256.0f) - mean * mean;
        rsum[r] = mean;
        rsq[r]  = rsqrtf(var + 1e-6f);
    }
    #pragma unroll
    for (int fn = 0; fn < 16; ++fn) {
        const int n = fn * 16 + ql;
        const float gn = g2[n], bn2 = b2[n];
        #pragma unroll
        for (int r = 0; r < 4; ++r) {
            const long m = m0 + waveM + g * 4 + r;
            float v = acc[fn][r];
            x2out[m * 256 + n] = (bf16)v;
            uout[m * 256 + n] = (bf16)((v - rsum[r]) * rsq[r] * gn + bn2);
        }
    }
}

// ------------------------------- launch ----------------------------------
extern "C" void kernel_launch(void* const* d_in, const int* in_sizes, int n_in,
                              void* d_out, int out_size, void* d_ws, size_t ws_size,
                              hipStream_t stream)
{
    (void)in_sizes; (void)n_in; (void)out_size; (void)ws_size;
    const float* x      = (const float*)d_in[0];
    const float* mask_h = (const float*)d_in[1];
    const float* mask_w = (const float*)d_in[2];
    const float* pos_w  = (const float*)d_in[3];
    const float* pos_b  = (const float*)d_in[4];
    const float* ln1_g  = (const float*)d_in[5];
    const float* ln1_b  = (const float*)d_in[6];
    const float* q_w    = (const float*)d_in[7];
    const float* q_b    = (const float*)d_in[8];
    const float* k_w    = (const float*)d_in[9];
    const float* k_b    = (const float*)d_in[10];
    const float* v_w    = (const float*)d_in[11];
    const float* v_b    = (const float*)d_in[12];
    const float* lepe_w = (const float*)d_in[13];
    const float* lepe_b = (const float*)d_in[14];
    const float* out_w  = (const float*)d_in[15];
    const float* out_b  = (const float*)d_in[16];
    const float* ln2_g  = (const float*)d_in[17];
    const float* ln2_b  = (const float*)d_in[18];
    const float* fc1_w  = (const float*)d_in[19];
    const float* fc1_b  = (const float*)d_in[20];
    const float* fc2_w  = (const float*)d_in[21];
    const float* fc2_b  = (const float*)d_in[22];

    char* ws = (char*)d_ws;
    size_t off = 0;
    auto alloc = [&](size_t bytes) -> void* {
        void* p = ws + off;
        off += (bytes + 255) & ~(size_t)255;
        return p;
    };
    const int M = NPIX;
    bf16*  x1     = (bf16*) alloc((size_t)M * 256 * 2);       // x + posconv (bf16 residual)
    bf16*  tln    = (bf16*) alloc((size_t)M * 256 * 2);       // LN1 out
    bf16*  qkv3   = (bf16*) alloc((size_t)M * 768 * 2);       // q|k|v PLANAR (3x M*256)
    bf16*  lepeb  = (bf16*) alloc((size_t)M * 256 * 2);       // lepe; later reused as LN2 out
    bf16*  vwb    = (bf16*) alloc((size_t)M * 256 * 2);       // width-attention output
    bf16*  obuf   = (bf16*) alloc((size_t)M * 256 * 2);       // height-attn out + lepe
    bf16*  x2b    = (bf16*) alloc((size_t)M * 256 * 2);       // x2 trunk (bf16)
    bf16*  wt_qkv = (bf16*) alloc((size_t)768 * 256 * 2);
    bf16*  wt_out = (bf16*) alloc((size_t)256 * 256 * 2);
    bf16*  wt_fc1 = (bf16*) alloc((size_t)1024 * 256 * 2);
    bf16*  wt_fc2 = (bf16*) alloc((size_t)256 * 1024 * 2);
    float* qkvb   = (float*)alloc(768 * 4);
    bf16*  qpl    = qkv3;
    bf16*  kpl    = qkv3 + (size_t)M * 256;
    bf16*  vpl    = qkv3 + (size_t)M * 512;
    bf16*  h1     = tln;   // [M][1024] bf16 = 102.76MB, spans tln+qkv3
    float* outf   = (float*)d_out;

    // 0+1+2. weight prep (+bias) AND posconv+LN1 (pixel-pair) in one launch
    pre_kernel<<<6272 + 3075, 256, 0, stream>>>(
        x, pos_w, pos_b, ln1_g, ln1_b, x1, tln,
        q_w, k_w, v_w, out_w, fc1_w, fc2_w, q_b, k_b, v_b,
        wt_qkv, wt_out, wt_fc1, wt_fc2, qkvb);

    // 3. q/k/v planes = tln @ [q|k*s|v] + bias  (196 m-tiles x 6 n-tiles)
    gemm_kernel<false, false, true, true><<<196 * 6, 512, 0, stream>>>(
        tln, wt_qkv, qkvb, nullptr, qkv3, M, 768, 256);
    // 4. lepe = dwconv5x5(v), register-blocked vertical-4, ww-fastest order
    lepe_kernel<<<1568, 256, 0, stream>>>(vpl, lepe_w, lepe_b, lepeb);
    // 5. width-axis attention -> vw
    attn_mfma_kernel<true><<<1792, 256, 0, stream>>>(qpl, kpl, vpl, mask_w, nullptr, vwb);
    // 6. height-axis attention (V = vw) + lepe -> obuf
    attn_mfma_kernel<false><<<1792, 256, 0, stream>>>(qpl, kpl, vwb, mask_h, lepeb, obuf);
    // 7+8. x2 = x1 + obuf @ out_w + out_b -> x2b (bf16);  u = LN2(x2) -> lepeb
    outln_kernel<<<392, 512, 0, stream>>>(
        obuf, wt_out, out_b, x1, ln2_g, ln2_b, x2b, lepeb);
    // 9. h1 = gelu(u @ fc1_w + fc1_b)  (196 x 8 tiles)
    gemm_kernel<true, false, true, false><<<196 * 8, 512, 0, stream>>>(
        lepeb, wt_fc1, fc1_b, nullptr, h1, M, 1024, 256);
    // 10. d_out = x2 + h1 @ fc2_w + fc2_b  (196 x 2 tiles, fp32 out)
    gemm_kernel<false, true, false, false><<<196 * 2, 512, 0, stream>>>(
        h1, wt_fc2, fc2_b, x2b, outf, M, 256, 1024);
}